// Round 9
// baseline (402.805 us; speedup 1.0000x reference)
//
#include <hip/hip_runtime.h>
#include <stdint.h>
#include <math.h>

// ---------------------------------------------------------------------------
// MPCN (B=128, R=30, L=60, D=300, V=50000, P=3), f32 end-to-end.
// Round 9: kill the idle weights prelude — Wp/A1/bias-chains ride inside
// gate_kernel (600->753 blocks), KG rides inside rev128 (900->975 blocks);
// wave-shfl fix for the uncoalesced t1s matvec. Selection-critical math
// (S, REV, Wp, Bp, TP/IP, gumbel argmax) bitwise-stable vs r8.
// ---------------------------------------------------------------------------

__host__ __device__ static inline void tf2x32(uint32_t k0, uint32_t k1,
                                              uint32_t x0, uint32_t x1,
                                              uint32_t* o0, uint32_t* o1) {
  uint32_t ks[3] = {k0, k1, k0 ^ k1 ^ 0x1BD11BDAu};
  x0 += ks[0]; x1 += ks[1];
  const int rotA[4] = {13, 15, 26, 6};
  const int rotB[4] = {17, 29, 16, 24};
#pragma unroll
  for (int i = 0; i < 5; ++i) {
    const int* rot = ((i & 1) == 0) ? rotA : rotB;
#pragma unroll
    for (int j = 0; j < 4; ++j) {
      x0 += x1;
      x1 = (x1 << rot[j]) | (x1 >> (32 - rot[j]));
      x1 ^= x0;
    }
    x0 += ks[(i + 1) % 3];
    x1 += ks[(i + 2) % 3] + (uint32_t)(i + 1);
  }
  *o0 = x0; *o1 = x1;
}

struct GKeys { uint32_t v[12]; };
struct Ptr6 {
  const float* X[6];
  const float* W[6];
  const float* Bb[6];
  float*       Y[6];
};

__device__ static inline float jax_gumbel32(uint32_t k0, uint32_t k1, uint32_t idx) {
  uint32_t o0, o1;
  tf2x32(k0, k1, 0u, idx, &o0, &o1);
  uint32_t bits = o0 ^ o1;
  float f = __uint_as_float((bits >> 9) | 0x3f800000u) - 1.0f;
  float u = (f > 0.0f) ? f : 1.17549435e-38f;
  return -logf(-logf(u));
}

#define MODE_NN 0
#define MODE_NT 1
#define MODE_TN 2

// 64x64 f32 GEMM tile, K=N=300, ld=300, caller-provided LDS arena
// (needs 2*20*68 = 2720 floats). Optional transposed second output Yt.
template <int MODE, bool BIAS>
__device__ __forceinline__ void gemm_tile(float* __restrict__ sm,
                                          const float* __restrict__ X,
                                          const float* __restrict__ W,
                                          const float* __restrict__ bias,
                                          float* __restrict__ Y,
                                          float* __restrict__ Yt,
                                          int M, int bm, int n0, int t) {
  float (*Xs)[68] = (float(*)[68])sm;
  float (*Ws_)[68] = (float(*)[68])(sm + 20 * 68);
  const bool act = t < 256;
  int tm4 = ((t >> 4) & 15) * 4;
  int tn4 = (t & 15) * 4;
  float acc[4][4] = {{0.f}};
  int xm = t >> 2;
  int xk = (t & 3) * 5;
  for (int k0 = 0; k0 < 300; k0 += 20) {
    if (act) {
      if (MODE == MODE_TN) {
#pragma unroll
        for (int i = 0; i < 5; ++i) {
          int flat = t + i * 256;
          int kk = flat >> 6, nn = flat & 63;
          int r = bm + nn;
          Xs[kk][nn] = (r < 300) ? X[(size_t)(k0 + kk) * 300 + r] : 0.f;
        }
      } else {
        int rr = bm + xm; if (rr >= M) rr = M - 1;
        const float* xp = X + (size_t)rr * 300 + k0 + xk;
#pragma unroll
        for (int j = 0; j < 5; ++j) Xs[xk + j][xm] = xp[j];
      }
      if (MODE == MODE_NT) {
        int d = n0 + xm;
        bool ok = d < 300;
        const float* wp = W + (size_t)d * 300 + k0 + xk;
#pragma unroll
        for (int j = 0; j < 5; ++j) Ws_[xk + j][xm] = ok ? wp[j] : 0.f;
      } else {
#pragma unroll
        for (int i = 0; i < 5; ++i) {
          int flat = t + i * 256;
          int kk = flat >> 6, nn = flat & 63;
          int col = n0 + nn;
          Ws_[kk][nn] = (col < 300) ? W[(size_t)(k0 + kk) * 300 + col] : 0.f;
        }
      }
    }
    __syncthreads();
    if (act) {
#pragma unroll
      for (int kk = 0; kk < 20; ++kk) {
        const float4 a = *(const float4*)&Xs[kk][tm4];
        const float4 w = *(const float4*)&Ws_[kk][tn4];
        float av[4] = {a.x, a.y, a.z, a.w};
        float wv[4] = {w.x, w.y, w.z, w.w};
#pragma unroll
        for (int i = 0; i < 4; ++i)
#pragma unroll
          for (int j = 0; j < 4; ++j)
            acc[i][j] = fmaf(av[i], wv[j], acc[i][j]);
      }
    }
    __syncthreads();
  }
  if (!act) return;
  float bv[4] = {0.f, 0.f, 0.f, 0.f};
  if (BIAS) {
#pragma unroll
    for (int j = 0; j < 4; ++j) {
      int col = n0 + tn4 + j;
      if (col < 300) bv[j] = bias[col];
    }
  }
#pragma unroll
  for (int i = 0; i < 4; ++i) {
    int row = bm + tm4 + i;
    if (row < M) {
      float* yp = Y + (size_t)row * 300 + n0 + tn4;
#pragma unroll
      for (int j = 0; j < 4; ++j) {
        int col = n0 + tn4 + j;
        if (col < 300) yp[j] = acc[i][j] + bv[j];
      }
    }
  }
  if (Yt) {
#pragma unroll
    for (int i = 0; i < 4; ++i) {
      int row = bm + tm4 + i;
      if (row < 300) {
#pragma unroll
        for (int j = 0; j < 4; ++j) {
          int col = n0 + tn4 + j;
          if (col < 300) Yt[(size_t)col * 300 + row] = acc[i][j];
        }
      }
    }
  }
}

// L1: gather-sum, minimal-resource, 15-deep ILP (ascending-l adds).
__global__ __launch_bounds__(320)
void gather_kernel(const int* __restrict__ uRevs, const int* __restrict__ iRevs,
                   const float* __restrict__ uEmb, const float* __restrict__ iEmb,
                   float* __restrict__ S) {
  int bid = blockIdx.x;   // 0..1919
  int t = threadIdx.x;
  __shared__ int toks[4][60];
  if (t < 240) {
    int rr = t / 60, l = t - rr * 60;
    int grow = bid * 4 + rr;
    int side = grow / 3840;
    int row = grow - side * 3840;
    const int* revs = side ? iRevs : uRevs;
    toks[rr][l] = revs[row * 60 + l];
  }
  __syncthreads();
  if (t < 300) {
    int sub = t / 75;
    int q4 = (t - sub * 75) * 4;
    int grow = bid * 4 + sub;
    int side = grow / 3840;
    const float* emb = side ? iEmb : uEmb;
    const int* tk = toks[sub];
    float ax = 0.f, ay = 0.f, az = 0.f, aw = 0.f;
#pragma unroll
    for (int l0 = 0; l0 < 60; l0 += 15) {
      float4 v[15];
#pragma unroll
      for (int qq = 0; qq < 15; ++qq)
        v[qq] = *(const float4*)&emb[(size_t)tk[l0 + qq] * 300 + q4];
#pragma unroll
      for (int qq = 0; qq < 15; ++qq) {
        ax += v[qq].x; ay += v[qq].y; az += v[qq].z; aw += v[qq].w;
      }
    }
    float4 r = {ax, ay, az, aw};
    *(float4*)&S[(size_t)grow * 300 + q4] = r;
  }
}

// L2: fused review gate (blocks 0..599, bitwise r1 arithmetic) +
// Wp = Wur^T@Mr (600..674) + A1 = Mw@Wiw (675..749) + bias chains (750..752).
__global__ __launch_bounds__(256)
void gate_kernel(const float* __restrict__ S,
                 const float* __restrict__ g1w, const float* __restrict__ g1b,
                 const float* __restrict__ g2w, const float* __restrict__ g2b,
                 float* __restrict__ REV,
                 const float* __restrict__ Wur, const float* __restrict__ Mr,
                 const float* __restrict__ Mw, const float* __restrict__ Wiw,
                 const float* __restrict__ Wuw,
                 const float* __restrict__ bur, const float* __restrict__ buw,
                 const float* __restrict__ biw,
                 float* __restrict__ Wp, float* __restrict__ A1,
                 float* __restrict__ CGH, float* __restrict__ Bp) {
  __shared__ __align__(16) float arena[4080];  // 16320 B
  int bid = blockIdx.x, t = threadIdx.x;
  if (bid < 600) {
    float (*Xs)[68] = (float(*)[68])arena;
    float (*Ws1)[68] = (float(*)[68])(arena + 1360);
    float (*Ws2)[68] = (float(*)[68])(arena + 2720);
    int bm = (bid / 5) * 64;
    int n0 = (bid % 5) * 64;
    int tm4 = (t >> 4) * 4;
    int tn4 = (t & 15) * 4;
    float acc1[4][4] = {{0.f}};
    float acc2[4][4] = {{0.f}};
    int xm = t >> 2;
    int xk = (t & 3) * 5;
    for (int k0 = 0; k0 < 300; k0 += 20) {
      const float* xp = S + (size_t)(bm + xm) * 300 + k0 + xk;
#pragma unroll
      for (int j = 0; j < 5; ++j) Xs[xk + j][xm] = xp[j];
      {
        int dIdx = n0 + xm;
        bool ok = dIdx < 300;
        const float* wp1 = g1w + (size_t)dIdx * 300 + k0 + xk;
        const float* wp2 = g2w + (size_t)dIdx * 300 + k0 + xk;
#pragma unroll
        for (int j = 0; j < 5; ++j) Ws1[xk + j][xm] = ok ? wp1[j] : 0.f;
#pragma unroll
        for (int j = 0; j < 5; ++j) Ws2[xk + j][xm] = ok ? wp2[j] : 0.f;
      }
      __syncthreads();
#pragma unroll
      for (int kk = 0; kk < 20; ++kk) {
        const float4 a = *(const float4*)&Xs[kk][tm4];
        const float4 w1 = *(const float4*)&Ws1[kk][tn4];
        const float4 w2 = *(const float4*)&Ws2[kk][tn4];
        float av[4] = {a.x, a.y, a.z, a.w};
        float w1v[4] = {w1.x, w1.y, w1.z, w1.w};
        float w2v[4] = {w2.x, w2.y, w2.z, w2.w};
#pragma unroll
        for (int i = 0; i < 4; ++i)
#pragma unroll
          for (int j = 0; j < 4; ++j) {
            acc1[i][j] = fmaf(av[i], w1v[j], acc1[i][j]);
            acc2[i][j] = fmaf(av[i], w2v[j], acc2[i][j]);
          }
      }
      __syncthreads();
    }
#pragma unroll
    for (int i = 0; i < 4; ++i) {
      int row = bm + tm4 + i;
      float* yp = REV + (size_t)row * 300 + n0 + tn4;
#pragma unroll
      for (int j = 0; j < 4; ++j) {
        int col = n0 + tn4 + j;
        if (col < 300) {
          float a = acc1[i][j] + g1b[col];
          float b = acc2[i][j] + g2b[col];
          yp[j] = (1.f / (1.f + expf(-a))) * tanhf(b);
        }
      }
    }
  } else if (bid < 675) {
    int zi = bid - 600, z = zi / 25, r = zi % 25;
    gemm_tile<MODE_TN, false>(arena, Wur + (size_t)z * 90000, Mr + (size_t)z * 90000,
                              nullptr, Wp + (size_t)z * 90000, nullptr,
                              300, (r / 5) * 64, (r % 5) * 64, t);
  } else if (bid < 750) {
    int zi = bid - 675, z = zi / 25, r = zi % 25;
    gemm_tile<MODE_NN, false>(arena, Mw + (size_t)z * 90000, Wiw + (size_t)z * 90000,
                              nullptr, A1 + (size_t)z * 90000, nullptr,
                              300, (r / 5) * 64, (r % 5) * 64, t);
  } else {
    // bias chains: c_g = Wuw^T(Mw biw) [t1s via coalesced wave-shfl],
    // c_h = Wiw^T(Mw^T buw), b' = Mr^T bur (both already coalesced, bitwise kept)
    int z = bid - 750;
    float* vb = arena;
    float* t1s = arena + 304;
    float* t2s = arena + 608;
    const float* Mwz = Mw + (size_t)z * 90000;
    const float* Wuwz = Wuw + (size_t)z * 90000;
    const float* Wiwz = Wiw + (size_t)z * 90000;
    const float* Mrz = Mr + (size_t)z * 90000;
    for (int k = t; k < 300; k += 256) vb[k] = biw[z * 300 + k];
    __syncthreads();
    {
      int w = t >> 6, j = t & 63;
      for (int i = 0; i < 75; ++i) {
        int e = w * 75 + i;
        float partial = 0.f;
#pragma unroll
        for (int c = 0; c < 5; ++c) {
          int k = j + c * 64;
          if (k < 300) partial = fmaf(Mwz[(size_t)e * 300 + k], vb[k], partial);
        }
#pragma unroll
        for (int m = 32; m >= 1; m >>= 1) partial += __shfl_xor(partial, m);
        if (j == 0) t1s[e] = partial;
      }
    }
    __syncthreads();
    for (int k = t; k < 300; k += 256) {
      float a = 0.f;
      for (int d = 0; d < 300; ++d) a = fmaf(Wuwz[(size_t)d * 300 + k], t1s[d], a);
      CGH[(size_t)(2 * z) * 300 + k] = a;
    }
    __syncthreads();
    for (int d = t; d < 300; d += 256) vb[d] = buw[z * 300 + d];
    __syncthreads();
    for (int e = t; e < 300; e += 256) {
      float a = 0.f;
      for (int d = 0; d < 300; ++d) a = fmaf(Mwz[(size_t)d * 300 + e], vb[d], a);
      t2s[e] = a;
    }
    __syncthreads();
    for (int k = t; k < 300; k += 256) {
      float a = 0.f;
      for (int e = 0; e < 300; ++e) a = fmaf(Wiwz[(size_t)e * 300 + k], t2s[e], a);
      CGH[(size_t)(2 * z + 1) * 300 + k] = a;
    }
    __syncthreads();
    for (int d = t; d < 300; d += 256) vb[d] = bur[z * 300 + d];
    __syncthreads();
    for (int e = t; e < 300; e += 256) {
      float a = 0.f;
      for (int d = 0; d < 300; ++d) a = fmaf(Mrz[(size_t)d * 300 + e], vb[d], a);
      Bp[z * 300 + e] = a;
    }
  }
}

// L3: TP/IP GEMMs (blocks 0..899, same per-tile arithmetic as r8) +
// KG = Wuw^T@A1 with transposed copy (900..974).
__global__ __launch_bounds__(256)
void rev128_kernel(Ptr6 P, const float* __restrict__ Wuw,
                   const float* __restrict__ A1,
                   float* __restrict__ KG, float* __restrict__ KGT) {
  __shared__ __align__(16) float arena[4080];  // 16320 B
  int bid = blockIdx.x, t = threadIdx.x;
  if (bid >= 900) {
    int zi = bid - 900, z = zi / 25, r = zi % 25;
    gemm_tile<MODE_TN, false>(arena, Wuw + (size_t)z * 90000, A1 + (size_t)z * 90000,
                              nullptr, KG + (size_t)z * 90000,
                              KGT + (size_t)z * 90000,
                              300, (r / 5) * 64, (r % 5) * 64, t);
    return;
  }
  int z = bid / 150;
  int rem = bid - z * 150;
  int bm = (rem % 30) * 128;
  int n0 = (rem / 30) * 64;
  const bool nt = z >= 3;
  const float* __restrict__ X = P.X[z];
  const float* __restrict__ W = P.W[z];
  const float* __restrict__ bias = P.Bb[z];
  float* __restrict__ Y = P.Y[z];
  float (*Xs)[136] = (float(*)[136])arena;            // 20*136 = 2720
  float (*Ws_)[68] = (float(*)[68])(arena + 2720);    // 20*68  = 1360
  int tm8 = (t >> 4) * 8, tn4 = (t & 15) * 4;
  float acc[8][4] = {{0.f}};
  int xm = t >> 1, xk = (t & 1) * 10;
  int wm = t >> 2, wk = (t & 3) * 5;
  for (int k0 = 0; k0 < 300; k0 += 20) {
    const float* xp = X + (size_t)(bm + xm) * 300 + k0 + xk;
#pragma unroll
    for (int j = 0; j < 10; ++j) Xs[xk + j][xm] = xp[j];
    if (nt) {
      int d = n0 + wm;
      bool ok = d < 300;
      const float* wp = W + (size_t)d * 300 + k0 + wk;
#pragma unroll
      for (int j = 0; j < 5; ++j) Ws_[wk + j][wm] = ok ? wp[j] : 0.f;
    } else {
#pragma unroll
      for (int i = 0; i < 5; ++i) {
        int flat = t + i * 256;
        int kk = flat >> 6, nn = flat & 63;
        int col = n0 + nn;
        Ws_[kk][nn] = (col < 300) ? W[(size_t)(k0 + kk) * 300 + col] : 0.f;
      }
    }
    __syncthreads();
#pragma unroll
    for (int kk = 0; kk < 20; ++kk) {
      const float4 a0 = *(const float4*)&Xs[kk][tm8];
      const float4 a1 = *(const float4*)&Xs[kk][tm8 + 4];
      const float4 w = *(const float4*)&Ws_[kk][tn4];
      float av[8] = {a0.x, a0.y, a0.z, a0.w, a1.x, a1.y, a1.z, a1.w};
      float wv[4] = {w.x, w.y, w.z, w.w};
#pragma unroll
      for (int i = 0; i < 8; ++i)
#pragma unroll
        for (int j = 0; j < 4; ++j)
          acc[i][j] = fmaf(av[i], wv[j], acc[i][j]);
    }
    __syncthreads();
  }
  float bv[4];
#pragma unroll
  for (int j = 0; j < 4; ++j) {
    int col = n0 + tn4 + j;
    bv[j] = (col < 300) ? bias[col] : 0.f;
  }
#pragma unroll
  for (int i = 0; i < 8; ++i) {
    float* yp = Y + (size_t)(bm + tm8 + i) * 300 + n0 + tn4;
#pragma unroll
    for (int j = 0; j < 4; ++j) {
      int col = n0 + tn4 + j;
      if (col < 300) yp[j] = acc[i][j] + bv[j];
    }
  }
}

// L4: review scores (float4 dot) + gumbel-argmax + fused MEAN.
__global__ __launch_bounds__(256)
void argmax_mean_kernel(const float* __restrict__ Tall, const float* __restrict__ Iall,
                        const int* __restrict__ uRevs, const int* __restrict__ iRevs,
                        const float* __restrict__ uEmb, const float* __restrict__ iEmb,
                        int* __restrict__ idxU, int* __restrict__ idxI,
                        float* __restrict__ MEAN, GKeys K) {
  int b = blockIdx.x, z = blockIdx.y, t = threadIdx.x;
  uint32_t ku0 = K.v[z * 4], ku1 = K.v[z * 4 + 1];
  uint32_t ki0 = K.v[z * 4 + 2], ki1 = K.v[z * 4 + 3];
  __shared__ __align__(16) float Is[30 * 304];
  __shared__ float Sc[900];
  __shared__ float us[30], vs[30];
  __shared__ int selU, selI;
  __shared__ int toksI_s[60], toksU_s[60];
  const float* Tb = Tall + (size_t)z * 1152000 + (size_t)b * 9000;
  const float* Ib = Iall + (size_t)z * 1152000 + (size_t)b * 9000;
  for (int fc = t; fc < 2250; fc += 256) {
    int r = fc / 75, q = fc - r * 75;
    *(float4*)&Is[r * 304 + q * 4] = *(const float4*)&Ib[r * 300 + q * 4];
  }
  __syncthreads();
  for (int id = t; id < 900; id += 256) {
    int r = id / 30, c = id - r * 30;
    const float* tr = Tb + r * 300;
    const float* ic = Is + c * 304;
    float acc = 0.f;
    for (int k = 0; k < 300; k += 4) {
      float4 a = *(const float4*)&tr[k];
      float4 w = *(const float4*)&ic[k];
      acc = fmaf(a.x, w.x, acc);
      acc = fmaf(a.y, w.y, acc);
      acc = fmaf(a.z, w.z, acc);
      acc = fmaf(a.w, w.w, acc);
    }
    Sc[id] = acc;
  }
  __syncthreads();
  if (t < 30) {
    float m = -3.4e38f;
    for (int c = 0; c < 30; ++c) m = fmaxf(m, Sc[t * 30 + c]);
    us[t] = m + jax_gumbel32(ku0, ku1, (uint32_t)(b * 30 + t));
  } else if (t >= 64 && t < 94) {
    int s = t - 64;
    float m = -3.4e38f;
    for (int r = 0; r < 30; ++r) m = fmaxf(m, Sc[r * 30 + s]);
    vs[s] = m + jax_gumbel32(ki0, ki1, (uint32_t)(b * 30 + s));
  }
  __syncthreads();
  if (t == 0) {
    int best = 0; float bvv = us[0];
    for (int r = 1; r < 30; ++r) { if (us[r] > bvv) { bvv = us[r]; best = r; } }
    idxU[z * 128 + b] = best; selU = best;
  } else if (t == 1) {
    int best = 0; float bvv = vs[0];
    for (int s = 1; s < 30; ++s) { if (vs[s] > bvv) { bvv = vs[s]; best = s; } }
    idxI[z * 128 + b] = best; selI = best;
  }
  __syncthreads();
  if (t < 60) toksI_s[t] = iRevs[(b * 30 + selI) * 60 + t];
  else if (t >= 64 && t < 124) toksU_s[t - 64] = uRevs[(b * 30 + selU) * 60 + (t - 64)];
  __syncthreads();
  for (int dd = t; dd < 600; dd += 256) {
    int side = dd / 300;
    int d = dd - side * 300;
    const int* tk = side ? toksU_s : toksI_s;
    const float* em = side ? uEmb : iEmb;
    float acc = 0.f;
#pragma unroll
    for (int l0 = 0; l0 < 60; l0 += 10) {
      float v[10];
#pragma unroll
      for (int q = 0; q < 10; ++q)
        v[q] = em[(size_t)tk[l0 + q] * 300 + d];
#pragma unroll
      for (int q = 0; q < 10; ++q) acc += v[q];
    }
    MEAN[((size_t)(2 * z + side) * 128 + b) * 300 + d] = acc * (1.f / 60.f);
  }
}

// L5: per (b, side, p): gv = MEAN@K + c (fused); scores; softmax; weighted sum.
__global__ __launch_bounds__(256)
void word_rep_kernel(const int* __restrict__ uRevs, const int* __restrict__ iRevs,
                     const float* __restrict__ uEmb, const float* __restrict__ iEmb,
                     const int* __restrict__ idxU, const int* __restrict__ idxI,
                     const float* __restrict__ MEAN, const float* __restrict__ KG,
                     const float* __restrict__ KGT, const float* __restrict__ CGH,
                     float* __restrict__ JNT) {
  int b = blockIdx.x, side = blockIdx.y, p = blockIdx.z;
  int zz = 2 * p + side;
  const int* revs = side ? iRevs : uRevs;
  const float* emb = side ? iEmb : uEmb;
  int idx = side ? idxI[p * 128 + b] : idxU[p * 128 + b];
  const float* Kmat = (side ? KGT : KG) + (size_t)p * 90000;
  __shared__ int toks[60];
  __shared__ float ms[300];
  __shared__ float g_s[300];
  __shared__ float score[60];
  __shared__ float probs[64];
  int t = threadIdx.x;
  if (t < 60) toks[t] = revs[(b * 30 + idx) * 60 + t];
  const float* mrow = MEAN + ((size_t)zz * 128 + b) * 300;
  for (int d = t; d < 300; d += 256) ms[d] = mrow[d];
  __syncthreads();
  for (int k = t; k < 300; k += 256) {
    const float* kr = Kmat + (size_t)k * 300;
    float acc = 0.f;
    for (int e = 0; e < 300; e += 4) {
      float4 kv = *(const float4*)&kr[e];
      acc = fmaf(kv.x, ms[e], acc);
      acc = fmaf(kv.y, ms[e + 1], acc);
      acc = fmaf(kv.z, ms[e + 2], acc);
      acc = fmaf(kv.w, ms[e + 3], acc);
    }
    g_s[k] = acc + CGH[(size_t)zz * 300 + k];
  }
  __syncthreads();
  int w = t >> 6, j = t & 63;
  for (int i = 0; i < 15; ++i) {
    int l = w * 15 + i;
    const float* er = emb + (size_t)toks[l] * 300;
    float partial = 0.f;
#pragma unroll
    for (int c = 0; c < 5; ++c) {
      int k = j + c * 64;
      if (k < 300) partial = fmaf(er[k], g_s[k], partial);
    }
#pragma unroll
    for (int m = 32; m >= 1; m >>= 1) partial += __shfl_xor(partial, m);
    if (j == 0) score[l] = partial;
  }
  __syncthreads();
  if (w == 0) {
    float s = (j < 60) ? score[j] : -3.4e38f;
    float m = s;
#pragma unroll
    for (int mm = 32; mm >= 1; mm >>= 1) m = fmaxf(m, __shfl_xor(m, mm));
    float e = (j < 60) ? expf(s - m) : 0.f;
    float sum = e;
#pragma unroll
    for (int mm = 32; mm >= 1; mm >>= 1) sum += __shfl_xor(sum, mm);
    if (j < 60) probs[j] = e / sum;
  }
  __syncthreads();
  float* outp = JNT + (size_t)b * 1800 + side * 900 + p * 300;
  for (int d = t; d < 300; d += 256) {
    float acc = 0.f;
    for (int l0 = 0; l0 < 60; l0 += 6) {
      float e0 = emb[(size_t)toks[l0 + 0] * 300 + d];
      float e1 = emb[(size_t)toks[l0 + 1] * 300 + d];
      float e2 = emb[(size_t)toks[l0 + 2] * 300 + d];
      float e3 = emb[(size_t)toks[l0 + 3] * 300 + d];
      float e4 = emb[(size_t)toks[l0 + 4] * 300 + d];
      float e5 = emb[(size_t)toks[l0 + 5] * 300 + d];
      acc = fmaf(probs[l0 + 0], e0, acc);
      acc = fmaf(probs[l0 + 1], e1, acc);
      acc = fmaf(probs[l0 + 2], e2, acc);
      acc = fmaf(probs[l0 + 3], e3, acc);
      acc = fmaf(probs[l0 + 4], e4, acc);
      acc = fmaf(probs[l0 + 5], e5, acc);
    }
    outp[d] = acc;
  }
}

// L6: factorization machine.
__global__ __launch_bounds__(64)
void fm_kernel(const float* __restrict__ JNT, const float* __restrict__ w0,
               const float* __restrict__ fw, const float* __restrict__ fv,
               float* __restrict__ out) {
  int b = blockIdx.x, lane = threadIdx.x;
  const float* x = JNT + (size_t)b * 1800;
  float lin = 0.f;
  float t1[10], t2[10];
#pragma unroll
  for (int k = 0; k < 10; ++k) { t1[k] = 0.f; t2[k] = 0.f; }
  for (int j = lane; j < 1800; j += 64) {
    float xv = x[j];
    lin = fmaf(fw[j], xv, lin);
    float xx = xv * xv;
#pragma unroll
    for (int k = 0; k < 10; ++k) {
      float v = fv[j * 10 + k];
      t1[k] = fmaf(xv, v, t1[k]);
      t2[k] = fmaf(xx, v * v, t2[k]);
    }
  }
#pragma unroll
  for (int m = 32; m >= 1; m >>= 1) {
    lin += __shfl_xor(lin, m);
#pragma unroll
    for (int k = 0; k < 10; ++k) {
      t1[k] += __shfl_xor(t1[k], m);
      t2[k] += __shfl_xor(t2[k], m);
    }
  }
  if (lane == 0) {
    float inter = 0.f;
#pragma unroll
    for (int k = 0; k < 10; ++k) inter += t1[k] * t1[k] - t2[k];
    out[b] = w0[0] + lin + 0.5f * inter;
  }
}

extern "C" void kernel_launch(void* const* d_in, const int* in_sizes, int n_in,
                              void* d_out, int out_size, void* d_ws, size_t ws_size,
                              hipStream_t stream) {
  (void)in_sizes; (void)n_in; (void)out_size;
  const int*   uRevs = (const int*)d_in[0];
  const int*   iRevs = (const int*)d_in[1];
  const float* uEmb  = (const float*)d_in[2];
  const float* iEmb  = (const float*)d_in[3];
  const float* g1w   = (const float*)d_in[4];
  const float* g1b   = (const float*)d_in[5];
  const float* g2w   = (const float*)d_in[6];
  const float* g2b   = (const float*)d_in[7];
  const float* Mr    = (const float*)d_in[8];
  const float* Wur   = (const float*)d_in[9];
  const float* bur   = (const float*)d_in[10];
  const float* Wir   = (const float*)d_in[11];
  const float* bir   = (const float*)d_in[12];
  const float* Mw    = (const float*)d_in[13];
  const float* Wuw   = (const float*)d_in[14];
  const float* buw   = (const float*)d_in[15];
  const float* Wiw   = (const float*)d_in[16];
  const float* biw   = (const float*)d_in[17];
  const float* fmw0  = (const float*)d_in[18];
  const float* fmw   = (const float*)d_in[19];
  const float* fmv   = (const float*)d_in[20];
  float* out = (float*)d_out;

  float* ws = (float*)d_ws;
  // Layout (floats), lifetime overlays:
  //   S @0 (2,304,000) L1..L2 ; TPall @0 (3,456,000) L3..L4
  //   REV @3,456,000 (2,304,000) L2..L3 ; MEAN @3,456,000 (230,400) L4..
  //   JNT @3,916,800 ; idx @4,147,200 (768 int)
  //   IPall @5,760,000 (3,456,000) L3..L4
  //   A1 @9,216,000 ; Wp @9,486,000 ; KG @9,756,000 ; KGT @10,026,000 ;
  //   Bp @10,296,000 (900) ; CGH @10,296,900 (1800)
  const size_t NEED_BYTES = (size_t)10298700 * 4;
  if (ws_size < NEED_BYTES) return;

  float* S     = ws + 0;
  float* TPall = ws + 0;
  float* REV   = ws + 3456000;
  float* MEAN  = ws + 3456000;
  float* JNT   = ws + 3916800;
  int*   idxU  = (int*)(ws + 4147200);
  int*   idxI  = idxU + 384;
  float* IPall = ws + 5760000;
  float* A1    = ws + 9216000;
  float* Wp    = ws + 9486000;
  float* KG    = ws + 9756000;
  float* KGT   = ws + 10026000;
  float* Bp    = ws + 10296000;
  float* CGH   = ws + 10296900;

  // L1: gather-sum
  gather_kernel<<<dim3(1920), dim3(320), 0, stream>>>(
      uRevs, iRevs, uEmb, iEmb, S);

  // L2: review gate + Wp + A1 + bias chains
  gate_kernel<<<dim3(753), dim3(256), 0, stream>>>(
      S, g1w, g1b, g2w, g2b, REV,
      Wur, Mr, Mw, Wiw, Wuw, bur, buw, biw, Wp, A1, CGH, Bp);

  // L3: TP/IP GEMMs + KG (+KGT)
  {
    Ptr6 P;
    for (int z = 0; z < 3; ++z) {
      P.X[z] = REV;
      P.W[z] = Wp + (size_t)z * 90000;
      P.Bb[z] = Bp + z * 300;
      P.Y[z] = TPall + (size_t)z * 1152000;
      P.X[z + 3] = REV + (size_t)3840 * 300;
      P.W[z + 3] = Wir + (size_t)z * 90000;
      P.Bb[z + 3] = bir + z * 300;
      P.Y[z + 3] = IPall + (size_t)z * 1152000;
    }
    rev128_kernel<<<dim3(975), dim3(256), 0, stream>>>(P, Wuw, A1, KG, KGT);
  }

  // L4: gumbel-argmax + fused MEAN
  {
    GKeys K;
    for (int p = 0; p < 3; ++p) {
      tf2x32(0u, 42u, 0u, (uint32_t)(2 * p),     &K.v[p * 4],     &K.v[p * 4 + 1]);
      tf2x32(0u, 42u, 0u, (uint32_t)(2 * p + 1), &K.v[p * 4 + 2], &K.v[p * 4 + 3]);
    }
    argmax_mean_kernel<<<dim3(128, 3), dim3(256), 0, stream>>>(
        TPall, IPall, uRevs, iRevs, uEmb, iEmb, idxU, idxI, MEAN, K);
  }

  // L5: word-level reps (gv matvec fused in)
  word_rep_kernel<<<dim3(128, 2, 3), dim3(256), 0, stream>>>(
      uRevs, iRevs, uEmb, iEmb, idxU, idxI, MEAN, KG, KGT, CGH, JNT);

  // L6: factorization machine
  fm_kernel<<<dim3(128), dim3(64), 0, stream>>>(JNT, fmw0, fmw, fmv, out);
}

// Round 10
// 345.735 us; speedup vs baseline: 1.1651x; 1.1651x over previous
//
#include <hip/hip_runtime.h>
#include <stdint.h>
#include <math.h>

// ---------------------------------------------------------------------------
// MPCN (B=128, R=30, L=60, D=300, V=50000, P=3), f32 end-to-end.
// Round 10: the ~85 µs serial bias-chain tail (r8 weights / r9 gate) is
// broken into parallel low-depth pieces: stage A (t1s/t2s/Bp) rides in gate
// with wave-shfl + 15-deep ILP; stage B (c_g/c_h -> CGH) rides in rev128.
// Selection-critical math (S, REV, Wp, Bp, TP/IP, gumbel) bitwise-stable.
// ---------------------------------------------------------------------------

__host__ __device__ static inline void tf2x32(uint32_t k0, uint32_t k1,
                                              uint32_t x0, uint32_t x1,
                                              uint32_t* o0, uint32_t* o1) {
  uint32_t ks[3] = {k0, k1, k0 ^ k1 ^ 0x1BD11BDAu};
  x0 += ks[0]; x1 += ks[1];
  const int rotA[4] = {13, 15, 26, 6};
  const int rotB[4] = {17, 29, 16, 24};
#pragma unroll
  for (int i = 0; i < 5; ++i) {
    const int* rot = ((i & 1) == 0) ? rotA : rotB;
#pragma unroll
    for (int j = 0; j < 4; ++j) {
      x0 += x1;
      x1 = (x1 << rot[j]) | (x1 >> (32 - rot[j]));
      x1 ^= x0;
    }
    x0 += ks[(i + 1) % 3];
    x1 += ks[(i + 2) % 3] + (uint32_t)(i + 1);
  }
  *o0 = x0; *o1 = x1;
}

struct GKeys { uint32_t v[12]; };
struct Ptr6 {
  const float* X[6];
  const float* W[6];
  const float* Bb[6];
  float*       Y[6];
};

__device__ static inline float jax_gumbel32(uint32_t k0, uint32_t k1, uint32_t idx) {
  uint32_t o0, o1;
  tf2x32(k0, k1, 0u, idx, &o0, &o1);
  uint32_t bits = o0 ^ o1;
  float f = __uint_as_float((bits >> 9) | 0x3f800000u) - 1.0f;
  float u = (f > 0.0f) ? f : 1.17549435e-38f;
  return -logf(-logf(u));
}

#define MODE_NN 0
#define MODE_NT 1
#define MODE_TN 2

// 64x64 f32 GEMM tile, K=N=300, ld=300, caller-provided LDS arena
// (needs 2*20*68 = 2720 floats). Optional transposed second output Yt.
template <int MODE, bool BIAS>
__device__ __forceinline__ void gemm_tile(float* __restrict__ sm,
                                          const float* __restrict__ X,
                                          const float* __restrict__ W,
                                          const float* __restrict__ bias,
                                          float* __restrict__ Y,
                                          float* __restrict__ Yt,
                                          int M, int bm, int n0, int t) {
  float (*Xs)[68] = (float(*)[68])sm;
  float (*Ws_)[68] = (float(*)[68])(sm + 20 * 68);
  const bool act = t < 256;
  int tm4 = ((t >> 4) & 15) * 4;
  int tn4 = (t & 15) * 4;
  float acc[4][4] = {{0.f}};
  int xm = t >> 2;
  int xk = (t & 3) * 5;
  for (int k0 = 0; k0 < 300; k0 += 20) {
    if (act) {
      if (MODE == MODE_TN) {
#pragma unroll
        for (int i = 0; i < 5; ++i) {
          int flat = t + i * 256;
          int kk = flat >> 6, nn = flat & 63;
          int r = bm + nn;
          Xs[kk][nn] = (r < 300) ? X[(size_t)(k0 + kk) * 300 + r] : 0.f;
        }
      } else {
        int rr = bm + xm; if (rr >= M) rr = M - 1;
        const float* xp = X + (size_t)rr * 300 + k0 + xk;
#pragma unroll
        for (int j = 0; j < 5; ++j) Xs[xk + j][xm] = xp[j];
      }
      if (MODE == MODE_NT) {
        int d = n0 + xm;
        bool ok = d < 300;
        const float* wp = W + (size_t)d * 300 + k0 + xk;
#pragma unroll
        for (int j = 0; j < 5; ++j) Ws_[xk + j][xm] = ok ? wp[j] : 0.f;
      } else {
#pragma unroll
        for (int i = 0; i < 5; ++i) {
          int flat = t + i * 256;
          int kk = flat >> 6, nn = flat & 63;
          int col = n0 + nn;
          Ws_[kk][nn] = (col < 300) ? W[(size_t)(k0 + kk) * 300 + col] : 0.f;
        }
      }
    }
    __syncthreads();
    if (act) {
#pragma unroll
      for (int kk = 0; kk < 20; ++kk) {
        const float4 a = *(const float4*)&Xs[kk][tm4];
        const float4 w = *(const float4*)&Ws_[kk][tn4];
        float av[4] = {a.x, a.y, a.z, a.w};
        float wv[4] = {w.x, w.y, w.z, w.w};
#pragma unroll
        for (int i = 0; i < 4; ++i)
#pragma unroll
          for (int j = 0; j < 4; ++j)
            acc[i][j] = fmaf(av[i], wv[j], acc[i][j]);
      }
    }
    __syncthreads();
  }
  if (!act) return;
  float bv[4] = {0.f, 0.f, 0.f, 0.f};
  if (BIAS) {
#pragma unroll
    for (int j = 0; j < 4; ++j) {
      int col = n0 + tn4 + j;
      if (col < 300) bv[j] = bias[col];
    }
  }
#pragma unroll
  for (int i = 0; i < 4; ++i) {
    int row = bm + tm4 + i;
    if (row < M) {
      float* yp = Y + (size_t)row * 300 + n0 + tn4;
#pragma unroll
      for (int j = 0; j < 4; ++j) {
        int col = n0 + tn4 + j;
        if (col < 300) yp[j] = acc[i][j] + bv[j];
      }
    }
  }
  if (Yt) {
#pragma unroll
    for (int i = 0; i < 4; ++i) {
      int row = bm + tm4 + i;
      if (row < 300) {
#pragma unroll
        for (int j = 0; j < 4; ++j) {
          int col = n0 + tn4 + j;
          if (col < 300) Yt[(size_t)col * 300 + row] = acc[i][j];
        }
      }
    }
  }
}

// L1: gather-sum, minimal-resource, 15-deep ILP (ascending-l adds).
__global__ __launch_bounds__(320)
void gather_kernel(const int* __restrict__ uRevs, const int* __restrict__ iRevs,
                   const float* __restrict__ uEmb, const float* __restrict__ iEmb,
                   float* __restrict__ S) {
  int bid = blockIdx.x;   // 0..1919
  int t = threadIdx.x;
  __shared__ int toks[4][60];
  if (t < 240) {
    int rr = t / 60, l = t - rr * 60;
    int grow = bid * 4 + rr;
    int side = grow / 3840;
    int row = grow - side * 3840;
    const int* revs = side ? iRevs : uRevs;
    toks[rr][l] = revs[row * 60 + l];
  }
  __syncthreads();
  if (t < 300) {
    int sub = t / 75;
    int q4 = (t - sub * 75) * 4;
    int grow = bid * 4 + sub;
    int side = grow / 3840;
    const float* emb = side ? iEmb : uEmb;
    const int* tk = toks[sub];
    float ax = 0.f, ay = 0.f, az = 0.f, aw = 0.f;
#pragma unroll
    for (int l0 = 0; l0 < 60; l0 += 15) {
      float4 v[15];
#pragma unroll
      for (int qq = 0; qq < 15; ++qq)
        v[qq] = *(const float4*)&emb[(size_t)tk[l0 + qq] * 300 + q4];
#pragma unroll
      for (int qq = 0; qq < 15; ++qq) {
        ax += v[qq].x; ay += v[qq].y; az += v[qq].z; aw += v[qq].w;
      }
    }
    float4 r = {ax, ay, az, aw};
    *(float4*)&S[(size_t)grow * 300 + q4] = r;
  }
}

// L2: review gate (0..599) + Wp (600..674) + A1 (675..749) +
// stage-A bias pieces: t1s wave-shfl (750..761), t2s (762..767), Bp (768..773).
__global__ __launch_bounds__(256)
void gate_kernel(const float* __restrict__ S,
                 const float* __restrict__ g1w, const float* __restrict__ g1b,
                 const float* __restrict__ g2w, const float* __restrict__ g2b,
                 float* __restrict__ REV,
                 const float* __restrict__ Wur, const float* __restrict__ Mr,
                 const float* __restrict__ Mw, const float* __restrict__ Wiw,
                 const float* __restrict__ bur, const float* __restrict__ buw,
                 const float* __restrict__ biw,
                 float* __restrict__ Wp, float* __restrict__ A1,
                 float* __restrict__ T1S, float* __restrict__ T2S,
                 float* __restrict__ Bp) {
  __shared__ __align__(16) float arena[4080];  // 16320 B
  int bid = blockIdx.x, t = threadIdx.x;
  if (bid < 600) {
    float (*Xs)[68] = (float(*)[68])arena;
    float (*Ws1)[68] = (float(*)[68])(arena + 1360);
    float (*Ws2)[68] = (float(*)[68])(arena + 2720);
    int bm = (bid / 5) * 64;
    int n0 = (bid % 5) * 64;
    int tm4 = (t >> 4) * 4;
    int tn4 = (t & 15) * 4;
    float acc1[4][4] = {{0.f}};
    float acc2[4][4] = {{0.f}};
    int xm = t >> 2;
    int xk = (t & 3) * 5;
    for (int k0 = 0; k0 < 300; k0 += 20) {
      const float* xp = S + (size_t)(bm + xm) * 300 + k0 + xk;
#pragma unroll
      for (int j = 0; j < 5; ++j) Xs[xk + j][xm] = xp[j];
      {
        int dIdx = n0 + xm;
        bool ok = dIdx < 300;
        const float* wp1 = g1w + (size_t)dIdx * 300 + k0 + xk;
        const float* wp2 = g2w + (size_t)dIdx * 300 + k0 + xk;
#pragma unroll
        for (int j = 0; j < 5; ++j) Ws1[xk + j][xm] = ok ? wp1[j] : 0.f;
#pragma unroll
        for (int j = 0; j < 5; ++j) Ws2[xk + j][xm] = ok ? wp2[j] : 0.f;
      }
      __syncthreads();
#pragma unroll
      for (int kk = 0; kk < 20; ++kk) {
        const float4 a = *(const float4*)&Xs[kk][tm4];
        const float4 w1 = *(const float4*)&Ws1[kk][tn4];
        const float4 w2 = *(const float4*)&Ws2[kk][tn4];
        float av[4] = {a.x, a.y, a.z, a.w};
        float w1v[4] = {w1.x, w1.y, w1.z, w1.w};
        float w2v[4] = {w2.x, w2.y, w2.z, w2.w};
#pragma unroll
        for (int i = 0; i < 4; ++i)
#pragma unroll
          for (int j = 0; j < 4; ++j) {
            acc1[i][j] = fmaf(av[i], w1v[j], acc1[i][j]);
            acc2[i][j] = fmaf(av[i], w2v[j], acc2[i][j]);
          }
      }
      __syncthreads();
    }
#pragma unroll
    for (int i = 0; i < 4; ++i) {
      int row = bm + tm4 + i;
      float* yp = REV + (size_t)row * 300 + n0 + tn4;
#pragma unroll
      for (int j = 0; j < 4; ++j) {
        int col = n0 + tn4 + j;
        if (col < 300) {
          float a = acc1[i][j] + g1b[col];
          float b = acc2[i][j] + g2b[col];
          yp[j] = (1.f / (1.f + expf(-a))) * tanhf(b);
        }
      }
    }
  } else if (bid < 675) {
    int zi = bid - 600, z = zi / 25, r = zi % 25;
    gemm_tile<MODE_TN, false>(arena, Wur + (size_t)z * 90000, Mr + (size_t)z * 90000,
                              nullptr, Wp + (size_t)z * 90000, nullptr,
                              300, (r / 5) * 64, (r % 5) * 64, t);
  } else if (bid < 750) {
    int zi = bid - 675, z = zi / 25, r = zi % 25;
    gemm_tile<MODE_NN, false>(arena, Mw + (size_t)z * 90000, Wiw + (size_t)z * 90000,
                              nullptr, A1 + (size_t)z * 90000, nullptr,
                              300, (r / 5) * 64, (r % 5) * 64, t);
  } else if (bid < 762) {
    // t1s[z][e] = sum_k Mw[z][e,k] * biw[z][k]  (row-form, wave-shfl dots)
    int idx = bid - 750, z = idx >> 2, qb = idx & 3;
    const float* Mwz = Mw + (size_t)z * 90000;
    const float* bw = biw + z * 300;
    int w = t >> 6, j = t & 63;
    int e0 = qb * 75;
    for (int i = 0; i < 19; ++i) {
      int el = w + 4 * i;
      if (el < 75) {
        int e = e0 + el;
        float partial = 0.f;
#pragma unroll
        for (int c = 0; c < 5; ++c) {
          int k = j + c * 64;
          if (k < 300) partial = fmaf(Mwz[(size_t)e * 300 + k], bw[k], partial);
        }
#pragma unroll
        for (int m = 32; m >= 1; m >>= 1) partial += __shfl_xor(partial, m);
        if (j == 0) T1S[z * 300 + e] = partial;
      }
    }
  } else if (bid < 768) {
    // t2s[z][e] = sum_d Mw[z][d,e] * buw[z][d]  (column-form, ILP-15)
    int idx = bid - 762, z = idx >> 1, half = idx & 1;
    const float* Mwz = Mw + (size_t)z * 90000;
    float* vb = arena;
    for (int d = t; d < 300; d += 256) vb[d] = buw[z * 300 + d];
    __syncthreads();
    if (t < 150) {
      int e = half * 150 + t;
      float a = 0.f;
      for (int d0 = 0; d0 < 300; d0 += 15) {
        float mv[15];
#pragma unroll
        for (int q = 0; q < 15; ++q) mv[q] = Mwz[(size_t)(d0 + q) * 300 + e];
#pragma unroll
        for (int q = 0; q < 15; ++q) a = fmaf(mv[q], vb[d0 + q], a);
      }
      T2S[z * 300 + e] = a;
    }
  } else {
    // Bp[z][e] = sum_d Mr[z][d,e] * bur[z][d]  (column-form, ILP-15,
    // ascending-d sequential fmaf -> bitwise identical to r8 chain)
    int idx = bid - 768, z = idx >> 1, half = idx & 1;
    const float* Mrz = Mr + (size_t)z * 90000;
    float* vb = arena;
    for (int d = t; d < 300; d += 256) vb[d] = bur[z * 300 + d];
    __syncthreads();
    if (t < 150) {
      int e = half * 150 + t;
      float a = 0.f;
      for (int d0 = 0; d0 < 300; d0 += 15) {
        float mv[15];
#pragma unroll
        for (int q = 0; q < 15; ++q) mv[q] = Mrz[(size_t)(d0 + q) * 300 + e];
#pragma unroll
        for (int q = 0; q < 15; ++q) a = fmaf(mv[q], vb[d0 + q], a);
      }
      Bp[z * 300 + e] = a;
    }
  }
}

// L3: TP/IP GEMMs (0..899) + KG (900..974) + stage-B bias (975..986):
// c_g[k]=sum_d Wuw[d,k]*t1s[d]; c_h[k]=sum_e Wiw[e,k]*t2s[e] -> CGH.
__global__ __launch_bounds__(256)
void rev128_kernel(Ptr6 P, const float* __restrict__ Wuw,
                   const float* __restrict__ Wiw,
                   const float* __restrict__ A1,
                   float* __restrict__ KG, float* __restrict__ KGT,
                   const float* __restrict__ T1S, const float* __restrict__ T2S,
                   float* __restrict__ CGH) {
  __shared__ __align__(16) float arena[4080];  // 16320 B
  int bid = blockIdx.x, t = threadIdx.x;
  if (bid >= 975) {
    int idx = bid - 975;
    int z = idx >> 2;
    int r2 = idx & 3;
    int which = r2 >> 1, half = r2 & 1;
    const float* W = (which ? Wiw : Wuw) + (size_t)z * 90000;
    const float* tv = (which ? T2S : T1S) + z * 300;
    float* vb = arena;
    for (int d = t; d < 300; d += 256) vb[d] = tv[d];
    __syncthreads();
    if (t < 150) {
      int k = half * 150 + t;
      float a = 0.f;
      for (int d0 = 0; d0 < 300; d0 += 15) {
        float mv[15];
#pragma unroll
        for (int q = 0; q < 15; ++q) mv[q] = W[(size_t)(d0 + q) * 300 + k];
#pragma unroll
        for (int q = 0; q < 15; ++q) a = fmaf(mv[q], vb[d0 + q], a);
      }
      CGH[(size_t)(2 * z + which) * 300 + k] = a;
    }
    return;
  }
  if (bid >= 900) {
    int zi = bid - 900, z = zi / 25, r = zi % 25;
    gemm_tile<MODE_TN, false>(arena, Wuw + (size_t)z * 90000, A1 + (size_t)z * 90000,
                              nullptr, KG + (size_t)z * 90000,
                              KGT + (size_t)z * 90000,
                              300, (r / 5) * 64, (r % 5) * 64, t);
    return;
  }
  int z = bid / 150;
  int rem = bid - z * 150;
  int bm = (rem % 30) * 128;
  int n0 = (rem / 30) * 64;
  const bool nt = z >= 3;
  const float* __restrict__ X = P.X[z];
  const float* __restrict__ W = P.W[z];
  const float* __restrict__ bias = P.Bb[z];
  float* __restrict__ Y = P.Y[z];
  float (*Xs)[136] = (float(*)[136])arena;            // 20*136 = 2720
  float (*Ws_)[68] = (float(*)[68])(arena + 2720);    // 20*68  = 1360
  int tm8 = (t >> 4) * 8, tn4 = (t & 15) * 4;
  float acc[8][4] = {{0.f}};
  int xm = t >> 1, xk = (t & 1) * 10;
  int wm = t >> 2, wk = (t & 3) * 5;
  for (int k0 = 0; k0 < 300; k0 += 20) {
    const float* xp = X + (size_t)(bm + xm) * 300 + k0 + xk;
#pragma unroll
    for (int j = 0; j < 10; ++j) Xs[xk + j][xm] = xp[j];
    if (nt) {
      int d = n0 + wm;
      bool ok = d < 300;
      const float* wp = W + (size_t)d * 300 + k0 + wk;
#pragma unroll
      for (int j = 0; j < 5; ++j) Ws_[wk + j][wm] = ok ? wp[j] : 0.f;
    } else {
#pragma unroll
      for (int i = 0; i < 5; ++i) {
        int flat = t + i * 256;
        int kk = flat >> 6, nn = flat & 63;
        int col = n0 + nn;
        Ws_[kk][nn] = (col < 300) ? W[(size_t)(k0 + kk) * 300 + col] : 0.f;
      }
    }
    __syncthreads();
#pragma unroll
    for (int kk = 0; kk < 20; ++kk) {
      const float4 a0 = *(const float4*)&Xs[kk][tm8];
      const float4 a1 = *(const float4*)&Xs[kk][tm8 + 4];
      const float4 w = *(const float4*)&Ws_[kk][tn4];
      float av[8] = {a0.x, a0.y, a0.z, a0.w, a1.x, a1.y, a1.z, a1.w};
      float wv[4] = {w.x, w.y, w.z, w.w};
#pragma unroll
      for (int i = 0; i < 8; ++i)
#pragma unroll
        for (int j = 0; j < 4; ++j)
          acc[i][j] = fmaf(av[i], wv[j], acc[i][j]);
    }
    __syncthreads();
  }
  float bv[4];
#pragma unroll
  for (int j = 0; j < 4; ++j) {
    int col = n0 + tn4 + j;
    bv[j] = (col < 300) ? bias[col] : 0.f;
  }
#pragma unroll
  for (int i = 0; i < 8; ++i) {
    float* yp = Y + (size_t)(bm + tm8 + i) * 300 + n0 + tn4;
#pragma unroll
    for (int j = 0; j < 4; ++j) {
      int col = n0 + tn4 + j;
      if (col < 300) yp[j] = acc[i][j] + bv[j];
    }
  }
}

// L4: review scores (float4 dot) + gumbel-argmax + fused MEAN.
__global__ __launch_bounds__(256)
void argmax_mean_kernel(const float* __restrict__ Tall, const float* __restrict__ Iall,
                        const int* __restrict__ uRevs, const int* __restrict__ iRevs,
                        const float* __restrict__ uEmb, const float* __restrict__ iEmb,
                        int* __restrict__ idxU, int* __restrict__ idxI,
                        float* __restrict__ MEAN, GKeys K) {
  int b = blockIdx.x, z = blockIdx.y, t = threadIdx.x;
  uint32_t ku0 = K.v[z * 4], ku1 = K.v[z * 4 + 1];
  uint32_t ki0 = K.v[z * 4 + 2], ki1 = K.v[z * 4 + 3];
  __shared__ __align__(16) float Is[30 * 304];
  __shared__ float Sc[900];
  __shared__ float us[30], vs[30];
  __shared__ int selU, selI;
  __shared__ int toksI_s[60], toksU_s[60];
  const float* Tb = Tall + (size_t)z * 1152000 + (size_t)b * 9000;
  const float* Ib = Iall + (size_t)z * 1152000 + (size_t)b * 9000;
  for (int fc = t; fc < 2250; fc += 256) {
    int r = fc / 75, q = fc - r * 75;
    *(float4*)&Is[r * 304 + q * 4] = *(const float4*)&Ib[r * 300 + q * 4];
  }
  __syncthreads();
  for (int id = t; id < 900; id += 256) {
    int r = id / 30, c = id - r * 30;
    const float* tr = Tb + r * 300;
    const float* ic = Is + c * 304;
    float acc = 0.f;
    for (int k = 0; k < 300; k += 4) {
      float4 a = *(const float4*)&tr[k];
      float4 w = *(const float4*)&ic[k];
      acc = fmaf(a.x, w.x, acc);
      acc = fmaf(a.y, w.y, acc);
      acc = fmaf(a.z, w.z, acc);
      acc = fmaf(a.w, w.w, acc);
    }
    Sc[id] = acc;
  }
  __syncthreads();
  if (t < 30) {
    float m = -3.4e38f;
    for (int c = 0; c < 30; ++c) m = fmaxf(m, Sc[t * 30 + c]);
    us[t] = m + jax_gumbel32(ku0, ku1, (uint32_t)(b * 30 + t));
  } else if (t >= 64 && t < 94) {
    int s = t - 64;
    float m = -3.4e38f;
    for (int r = 0; r < 30; ++r) m = fmaxf(m, Sc[r * 30 + s]);
    vs[s] = m + jax_gumbel32(ki0, ki1, (uint32_t)(b * 30 + s));
  }
  __syncthreads();
  if (t == 0) {
    int best = 0; float bvv = us[0];
    for (int r = 1; r < 30; ++r) { if (us[r] > bvv) { bvv = us[r]; best = r; } }
    idxU[z * 128 + b] = best; selU = best;
  } else if (t == 1) {
    int best = 0; float bvv = vs[0];
    for (int s = 1; s < 30; ++s) { if (vs[s] > bvv) { bvv = vs[s]; best = s; } }
    idxI[z * 128 + b] = best; selI = best;
  }
  __syncthreads();
  if (t < 60) toksI_s[t] = iRevs[(b * 30 + selI) * 60 + t];
  else if (t >= 64 && t < 124) toksU_s[t - 64] = uRevs[(b * 30 + selU) * 60 + (t - 64)];
  __syncthreads();
  for (int dd = t; dd < 600; dd += 256) {
    int side = dd / 300;
    int d = dd - side * 300;
    const int* tk = side ? toksU_s : toksI_s;
    const float* em = side ? uEmb : iEmb;
    float acc = 0.f;
#pragma unroll
    for (int l0 = 0; l0 < 60; l0 += 10) {
      float v[10];
#pragma unroll
      for (int q = 0; q < 10; ++q)
        v[q] = em[(size_t)tk[l0 + q] * 300 + d];
#pragma unroll
      for (int q = 0; q < 10; ++q) acc += v[q];
    }
    MEAN[((size_t)(2 * z + side) * 128 + b) * 300 + d] = acc * (1.f / 60.f);
  }
}

// L5: per (b, side, p): gv = MEAN@K + c (fused); scores; softmax; weighted sum.
__global__ __launch_bounds__(256)
void word_rep_kernel(const int* __restrict__ uRevs, const int* __restrict__ iRevs,
                     const float* __restrict__ uEmb, const float* __restrict__ iEmb,
                     const int* __restrict__ idxU, const int* __restrict__ idxI,
                     const float* __restrict__ MEAN, const float* __restrict__ KG,
                     const float* __restrict__ KGT, const float* __restrict__ CGH,
                     float* __restrict__ JNT) {
  int b = blockIdx.x, side = blockIdx.y, p = blockIdx.z;
  int zz = 2 * p + side;
  const int* revs = side ? iRevs : uRevs;
  const float* emb = side ? iEmb : uEmb;
  int idx = side ? idxI[p * 128 + b] : idxU[p * 128 + b];
  const float* Kmat = (side ? KGT : KG) + (size_t)p * 90000;
  __shared__ int toks[60];
  __shared__ float ms[300];
  __shared__ float g_s[300];
  __shared__ float score[60];
  __shared__ float probs[64];
  int t = threadIdx.x;
  if (t < 60) toks[t] = revs[(b * 30 + idx) * 60 + t];
  const float* mrow = MEAN + ((size_t)zz * 128 + b) * 300;
  for (int d = t; d < 300; d += 256) ms[d] = mrow[d];
  __syncthreads();
  for (int k = t; k < 300; k += 256) {
    const float* kr = Kmat + (size_t)k * 300;
    float acc = 0.f;
    for (int e = 0; e < 300; e += 4) {
      float4 kv = *(const float4*)&kr[e];
      acc = fmaf(kv.x, ms[e], acc);
      acc = fmaf(kv.y, ms[e + 1], acc);
      acc = fmaf(kv.z, ms[e + 2], acc);
      acc = fmaf(kv.w, ms[e + 3], acc);
    }
    g_s[k] = acc + CGH[(size_t)zz * 300 + k];
  }
  __syncthreads();
  int w = t >> 6, j = t & 63;
  for (int i = 0; i < 15; ++i) {
    int l = w * 15 + i;
    const float* er = emb + (size_t)toks[l] * 300;
    float partial = 0.f;
#pragma unroll
    for (int c = 0; c < 5; ++c) {
      int k = j + c * 64;
      if (k < 300) partial = fmaf(er[k], g_s[k], partial);
    }
#pragma unroll
    for (int m = 32; m >= 1; m >>= 1) partial += __shfl_xor(partial, m);
    if (j == 0) score[l] = partial;
  }
  __syncthreads();
  if (w == 0) {
    float s = (j < 60) ? score[j] : -3.4e38f;
    float m = s;
#pragma unroll
    for (int mm = 32; mm >= 1; mm >>= 1) m = fmaxf(m, __shfl_xor(m, mm));
    float e = (j < 60) ? expf(s - m) : 0.f;
    float sum = e;
#pragma unroll
    for (int mm = 32; mm >= 1; mm >>= 1) sum += __shfl_xor(sum, mm);
    if (j < 60) probs[j] = e / sum;
  }
  __syncthreads();
  float* outp = JNT + (size_t)b * 1800 + side * 900 + p * 300;
  for (int d = t; d < 300; d += 256) {
    float acc = 0.f;
    for (int l0 = 0; l0 < 60; l0 += 6) {
      float e0 = emb[(size_t)toks[l0 + 0] * 300 + d];
      float e1 = emb[(size_t)toks[l0 + 1] * 300 + d];
      float e2 = emb[(size_t)toks[l0 + 2] * 300 + d];
      float e3 = emb[(size_t)toks[l0 + 3] * 300 + d];
      float e4 = emb[(size_t)toks[l0 + 4] * 300 + d];
      float e5 = emb[(size_t)toks[l0 + 5] * 300 + d];
      acc = fmaf(probs[l0 + 0], e0, acc);
      acc = fmaf(probs[l0 + 1], e1, acc);
      acc = fmaf(probs[l0 + 2], e2, acc);
      acc = fmaf(probs[l0 + 3], e3, acc);
      acc = fmaf(probs[l0 + 4], e4, acc);
      acc = fmaf(probs[l0 + 5], e5, acc);
    }
    outp[d] = acc;
  }
}

// L6: factorization machine.
__global__ __launch_bounds__(64)
void fm_kernel(const float* __restrict__ JNT, const float* __restrict__ w0,
               const float* __restrict__ fw, const float* __restrict__ fv,
               float* __restrict__ out) {
  int b = blockIdx.x, lane = threadIdx.x;
  const float* x = JNT + (size_t)b * 1800;
  float lin = 0.f;
  float t1[10], t2[10];
#pragma unroll
  for (int k = 0; k < 10; ++k) { t1[k] = 0.f; t2[k] = 0.f; }
  for (int j = lane; j < 1800; j += 64) {
    float xv = x[j];
    lin = fmaf(fw[j], xv, lin);
    float xx = xv * xv;
#pragma unroll
    for (int k = 0; k < 10; ++k) {
      float v = fv[j * 10 + k];
      t1[k] = fmaf(xv, v, t1[k]);
      t2[k] = fmaf(xx, v * v, t2[k]);
    }
  }
#pragma unroll
  for (int m = 32; m >= 1; m >>= 1) {
    lin += __shfl_xor(lin, m);
#pragma unroll
    for (int k = 0; k < 10; ++k) {
      t1[k] += __shfl_xor(t1[k], m);
      t2[k] += __shfl_xor(t2[k], m);
    }
  }
  if (lane == 0) {
    float inter = 0.f;
#pragma unroll
    for (int k = 0; k < 10; ++k) inter += t1[k] * t1[k] - t2[k];
    out[b] = w0[0] + lin + 0.5f * inter;
  }
}

extern "C" void kernel_launch(void* const* d_in, const int* in_sizes, int n_in,
                              void* d_out, int out_size, void* d_ws, size_t ws_size,
                              hipStream_t stream) {
  (void)in_sizes; (void)n_in; (void)out_size;
  const int*   uRevs = (const int*)d_in[0];
  const int*   iRevs = (const int*)d_in[1];
  const float* uEmb  = (const float*)d_in[2];
  const float* iEmb  = (const float*)d_in[3];
  const float* g1w   = (const float*)d_in[4];
  const float* g1b   = (const float*)d_in[5];
  const float* g2w   = (const float*)d_in[6];
  const float* g2b   = (const float*)d_in[7];
  const float* Mr    = (const float*)d_in[8];
  const float* Wur   = (const float*)d_in[9];
  const float* bur   = (const float*)d_in[10];
  const float* Wir   = (const float*)d_in[11];
  const float* bir   = (const float*)d_in[12];
  const float* Mw    = (const float*)d_in[13];
  const float* Wuw   = (const float*)d_in[14];
  const float* buw   = (const float*)d_in[15];
  const float* Wiw   = (const float*)d_in[16];
  const float* biw   = (const float*)d_in[17];
  const float* fmw0  = (const float*)d_in[18];
  const float* fmw   = (const float*)d_in[19];
  const float* fmv   = (const float*)d_in[20];
  float* out = (float*)d_out;

  float* ws = (float*)d_ws;
  // Layout (floats), lifetime overlays:
  //   S @0 (2,304,000) L1..L2 ; TPall @0 (3,456,000) L3..L4
  //   REV @3,456,000 (2,304,000) L2..L3 ; MEAN @3,456,000 (230,400) L4..
  //   JNT @3,916,800 ; idx @4,147,200 (768 int)
  //   IPall @5,760,000 (3,456,000) L3..L4
  //   A1 @9,216,000 ; Wp @9,486,000 ; KG @9,756,000 ; KGT @10,026,000 ;
  //   Bp @10,296,000 (900) ; CGH @10,296,900 (1800) ;
  //   T1S @10,298,700 (900) ; T2S @10,299,600 (900)
  const size_t NEED_BYTES = (size_t)10300500 * 4;
  if (ws_size < NEED_BYTES) return;

  float* S     = ws + 0;
  float* TPall = ws + 0;
  float* REV   = ws + 3456000;
  float* MEAN  = ws + 3456000;
  float* JNT   = ws + 3916800;
  int*   idxU  = (int*)(ws + 4147200);
  int*   idxI  = idxU + 384;
  float* IPall = ws + 5760000;
  float* A1    = ws + 9216000;
  float* Wp    = ws + 9486000;
  float* KG    = ws + 9756000;
  float* KGT   = ws + 10026000;
  float* Bp    = ws + 10296000;
  float* CGH   = ws + 10296900;
  float* T1S   = ws + 10298700;
  float* T2S   = ws + 10299600;

  // L1: gather-sum
  gather_kernel<<<dim3(1920), dim3(320), 0, stream>>>(
      uRevs, iRevs, uEmb, iEmb, S);

  // L2: review gate + Wp + A1 + stage-A bias pieces (t1s, t2s, Bp)
  gate_kernel<<<dim3(774), dim3(256), 0, stream>>>(
      S, g1w, g1b, g2w, g2b, REV,
      Wur, Mr, Mw, Wiw, bur, buw, biw, Wp, A1, T1S, T2S, Bp);

  // L3: TP/IP GEMMs + KG (+KGT) + stage-B bias (CGH)
  {
    Ptr6 P;
    for (int z = 0; z < 3; ++z) {
      P.X[z] = REV;
      P.W[z] = Wp + (size_t)z * 90000;
      P.Bb[z] = Bp + z * 300;
      P.Y[z] = TPall + (size_t)z * 1152000;
      P.X[z + 3] = REV + (size_t)3840 * 300;
      P.W[z + 3] = Wir + (size_t)z * 90000;
      P.Bb[z + 3] = bir + z * 300;
      P.Y[z + 3] = IPall + (size_t)z * 1152000;
    }
    rev128_kernel<<<dim3(987), dim3(256), 0, stream>>>(
        P, Wuw, Wiw, A1, KG, KGT, T1S, T2S, CGH);
  }

  // L4: gumbel-argmax + fused MEAN
  {
    GKeys K;
    for (int p = 0; p < 3; ++p) {
      tf2x32(0u, 42u, 0u, (uint32_t)(2 * p),     &K.v[p * 4],     &K.v[p * 4 + 1]);
      tf2x32(0u, 42u, 0u, (uint32_t)(2 * p + 1), &K.v[p * 4 + 2], &K.v[p * 4 + 3]);
    }
    argmax_mean_kernel<<<dim3(128, 3), dim3(256), 0, stream>>>(
        TPall, IPall, uRevs, iRevs, uEmb, iEmb, idxU, idxI, MEAN, K);
  }

  // L5: word-level reps (gv matvec fused in)
  word_rep_kernel<<<dim3(128, 2, 3), dim3(256), 0, stream>>>(
      uRevs, iRevs, uEmb, iEmb, idxU, idxI, MEAN, KG, KGT, CGH, JNT);

  // L6: factorization machine
  fm_kernel<<<dim3(128), dim3(64), 0, stream>>>(JNT, fmw0, fmw, fmv, out);
}

// Round 12
// 333.897 us; speedup vs baseline: 1.2064x; 1.0355x over previous
//
#include <hip/hip_runtime.h>
#include <stdint.h>
#include <math.h>

// ---------------------------------------------------------------------------
// MPCN (B=128, R=30, L=60, D=300, V=50000, P=3), f32 end-to-end.
// Round 12: r10 structure + CORRECT float4 staging (simple strided coverage
// loops — r11's branch-fused indexing left W-panel rows unstaged).
// Staging is bitwise-neutral: same values, same LDS slots, same math.
// ---------------------------------------------------------------------------

__host__ __device__ static inline void tf2x32(uint32_t k0, uint32_t k1,
                                              uint32_t x0, uint32_t x1,
                                              uint32_t* o0, uint32_t* o1) {
  uint32_t ks[3] = {k0, k1, k0 ^ k1 ^ 0x1BD11BDAu};
  x0 += ks[0]; x1 += ks[1];
  const int rotA[4] = {13, 15, 26, 6};
  const int rotB[4] = {17, 29, 16, 24};
#pragma unroll
  for (int i = 0; i < 5; ++i) {
    const int* rot = ((i & 1) == 0) ? rotA : rotB;
#pragma unroll
    for (int j = 0; j < 4; ++j) {
      x0 += x1;
      x1 = (x1 << rot[j]) | (x1 >> (32 - rot[j]));
      x1 ^= x0;
    }
    x0 += ks[(i + 1) % 3];
    x1 += ks[(i + 2) % 3] + (uint32_t)(i + 1);
  }
  *o0 = x0; *o1 = x1;
}

struct GKeys { uint32_t v[12]; };
struct Ptr6 {
  const float* X[6];
  const float* W[6];
  const float* Bb[6];
  float*       Y[6];
};

__device__ static inline float jax_gumbel32(uint32_t k0, uint32_t k1, uint32_t idx) {
  uint32_t o0, o1;
  tf2x32(k0, k1, 0u, idx, &o0, &o1);
  uint32_t bits = o0 ^ o1;
  float f = __uint_as_float((bits >> 9) | 0x3f800000u) - 1.0f;
  float u = (f > 0.0f) ? f : 1.17549435e-38f;
  return -logf(-logf(u));
}

#define MODE_NN 0
#define MODE_NT 1
#define MODE_TN 2

// 64x64 f32 GEMM tile, K=N=300, ld=300, caller-provided LDS arena
// (needs 2*20*68 = 2720 floats). Optional transposed second output Yt.
template <int MODE, bool BIAS>
__device__ __forceinline__ void gemm_tile(float* __restrict__ sm,
                                          const float* __restrict__ X,
                                          const float* __restrict__ W,
                                          const float* __restrict__ bias,
                                          float* __restrict__ Y,
                                          float* __restrict__ Yt,
                                          int M, int bm, int n0, int t) {
  float (*Xs)[68] = (float(*)[68])sm;
  float (*Ws_)[68] = (float(*)[68])(sm + 20 * 68);
  const bool act = t < 256;
  int tm4 = ((t >> 4) & 15) * 4;
  int tn4 = (t & 15) * 4;
  float acc[4][4] = {{0.f}};
  int xm = t >> 2;
  int xk = (t & 3) * 5;
  for (int k0 = 0; k0 < 300; k0 += 20) {
    if (act) {
      if (MODE == MODE_TN) {
#pragma unroll
        for (int i = 0; i < 5; ++i) {
          int flat = t + i * 256;
          int kk = flat >> 6, nn = flat & 63;
          int r = bm + nn;
          Xs[kk][nn] = (r < 300) ? X[(size_t)(k0 + kk) * 300 + r] : 0.f;
        }
      } else {
        int rr = bm + xm; if (rr >= M) rr = M - 1;
        const float* xp = X + (size_t)rr * 300 + k0 + xk;
#pragma unroll
        for (int j = 0; j < 5; ++j) Xs[xk + j][xm] = xp[j];
      }
      if (MODE == MODE_NT) {
        int d = n0 + xm;
        bool ok = d < 300;
        const float* wp = W + (size_t)d * 300 + k0 + xk;
#pragma unroll
        for (int j = 0; j < 5; ++j) Ws_[xk + j][xm] = ok ? wp[j] : 0.f;
      } else {
#pragma unroll
        for (int i = 0; i < 5; ++i) {
          int flat = t + i * 256;
          int kk = flat >> 6, nn = flat & 63;
          int col = n0 + nn;
          Ws_[kk][nn] = (col < 300) ? W[(size_t)(k0 + kk) * 300 + col] : 0.f;
        }
      }
    }
    __syncthreads();
    if (act) {
#pragma unroll
      for (int kk = 0; kk < 20; ++kk) {
        const float4 a = *(const float4*)&Xs[kk][tm4];
        const float4 w = *(const float4*)&Ws_[kk][tn4];
        float av[4] = {a.x, a.y, a.z, a.w};
        float wv[4] = {w.x, w.y, w.z, w.w};
#pragma unroll
        for (int i = 0; i < 4; ++i)
#pragma unroll
          for (int j = 0; j < 4; ++j)
            acc[i][j] = fmaf(av[i], wv[j], acc[i][j]);
      }
    }
    __syncthreads();
  }
  if (!act) return;
  float bv[4] = {0.f, 0.f, 0.f, 0.f};
  if (BIAS) {
#pragma unroll
    for (int j = 0; j < 4; ++j) {
      int col = n0 + tn4 + j;
      if (col < 300) bv[j] = bias[col];
    }
  }
#pragma unroll
  for (int i = 0; i < 4; ++i) {
    int row = bm + tm4 + i;
    if (row < M) {
      float* yp = Y + (size_t)row * 300 + n0 + tn4;
#pragma unroll
      for (int j = 0; j < 4; ++j) {
        int col = n0 + tn4 + j;
        if (col < 300) yp[j] = acc[i][j] + bv[j];
      }
    }
  }
  if (Yt) {
#pragma unroll
    for (int i = 0; i < 4; ++i) {
      int row = bm + tm4 + i;
      if (row < 300) {
#pragma unroll
        for (int j = 0; j < 4; ++j) {
          int col = n0 + tn4 + j;
          if (col < 300) Yt[(size_t)col * 300 + row] = acc[i][j];
        }
      }
    }
  }
}

// L1: gather-sum, minimal-resource, 15-deep ILP (ascending-l adds).
__global__ __launch_bounds__(320)
void gather_kernel(const int* __restrict__ uRevs, const int* __restrict__ iRevs,
                   const float* __restrict__ uEmb, const float* __restrict__ iEmb,
                   float* __restrict__ S) {
  int bid = blockIdx.x;   // 0..1919
  int t = threadIdx.x;
  __shared__ int toks[4][60];
  if (t < 240) {
    int rr = t / 60, l = t - rr * 60;
    int grow = bid * 4 + rr;
    int side = grow / 3840;
    int row = grow - side * 3840;
    const int* revs = side ? iRevs : uRevs;
    toks[rr][l] = revs[row * 60 + l];
  }
  __syncthreads();
  if (t < 300) {
    int sub = t / 75;
    int q4 = (t - sub * 75) * 4;
    int grow = bid * 4 + sub;
    int side = grow / 3840;
    const float* emb = side ? iEmb : uEmb;
    const int* tk = toks[sub];
    float ax = 0.f, ay = 0.f, az = 0.f, aw = 0.f;
#pragma unroll
    for (int l0 = 0; l0 < 60; l0 += 15) {
      float4 v[15];
#pragma unroll
      for (int qq = 0; qq < 15; ++qq)
        v[qq] = *(const float4*)&emb[(size_t)tk[l0 + qq] * 300 + q4];
#pragma unroll
      for (int qq = 0; qq < 15; ++qq) {
        ax += v[qq].x; ay += v[qq].y; az += v[qq].z; aw += v[qq].w;
      }
    }
    float4 r = {ax, ay, az, aw};
    *(float4*)&S[(size_t)grow * 300 + q4] = r;
  }
}

// L2: review gate (0..599, float4-staged) + Wp (600..674) + A1 (675..749) +
// stage-A bias pieces: t1s (750..761), t2s (762..767), Bp (768..773).
__global__ __launch_bounds__(256)
void gate_kernel(const float* __restrict__ S,
                 const float* __restrict__ g1w, const float* __restrict__ g1b,
                 const float* __restrict__ g2w, const float* __restrict__ g2b,
                 float* __restrict__ REV,
                 const float* __restrict__ Wur, const float* __restrict__ Mr,
                 const float* __restrict__ Mw, const float* __restrict__ Wiw,
                 const float* __restrict__ bur, const float* __restrict__ buw,
                 const float* __restrict__ biw,
                 float* __restrict__ Wp, float* __restrict__ A1,
                 float* __restrict__ T1S, float* __restrict__ T2S,
                 float* __restrict__ Bp) {
  __shared__ __align__(16) float arena[4080];  // 16320 B
  int bid = blockIdx.x, t = threadIdx.x;
  if (bid < 600) {
    float (*Xs)[68] = (float(*)[68])arena;
    float (*Ws1)[68] = (float(*)[68])(arena + 1360);
    float (*Ws2)[68] = (float(*)[68])(arena + 2720);
    int bm = (bid / 5) * 64;
    int n0 = (bid % 5) * 64;
    int tm4 = (t >> 4) * 4;
    int tn4 = (t & 15) * 4;
    float acc1[4][4] = {{0.f}};
    float acc2[4][4] = {{0.f}};
    for (int k0 = 0; k0 < 300; k0 += 20) {
      // X panel: 64 rows x 5 float4 = 320
      for (int fid = t; fid < 320; fid += 256) {
        int row = fid / 5, q = fid - row * 5;
        float4 v = *(const float4*)&S[(size_t)(bm + row) * 300 + k0 + q * 4];
        int kq = q * 4;
        Xs[kq + 0][row] = v.x; Xs[kq + 1][row] = v.y;
        Xs[kq + 2][row] = v.z; Xs[kq + 3][row] = v.w;
      }
      // W1 panel: 64 d x 5 float4 = 320 (NT form, zero-fill d>=300)
      for (int fid = t; fid < 320; fid += 256) {
        int dl = fid / 5, q = fid - dl * 5;
        int d = n0 + dl;
        float4 v = {0.f, 0.f, 0.f, 0.f};
        if (d < 300) v = *(const float4*)&g1w[(size_t)d * 300 + k0 + q * 4];
        int kq = q * 4;
        Ws1[kq + 0][dl] = v.x; Ws1[kq + 1][dl] = v.y;
        Ws1[kq + 2][dl] = v.z; Ws1[kq + 3][dl] = v.w;
      }
      // W2 panel
      for (int fid = t; fid < 320; fid += 256) {
        int dl = fid / 5, q = fid - dl * 5;
        int d = n0 + dl;
        float4 v = {0.f, 0.f, 0.f, 0.f};
        if (d < 300) v = *(const float4*)&g2w[(size_t)d * 300 + k0 + q * 4];
        int kq = q * 4;
        Ws2[kq + 0][dl] = v.x; Ws2[kq + 1][dl] = v.y;
        Ws2[kq + 2][dl] = v.z; Ws2[kq + 3][dl] = v.w;
      }
      __syncthreads();
#pragma unroll
      for (int kk = 0; kk < 20; ++kk) {
        const float4 a = *(const float4*)&Xs[kk][tm4];
        const float4 w1 = *(const float4*)&Ws1[kk][tn4];
        const float4 w2 = *(const float4*)&Ws2[kk][tn4];
        float av[4] = {a.x, a.y, a.z, a.w};
        float w1v[4] = {w1.x, w1.y, w1.z, w1.w};
        float w2v[4] = {w2.x, w2.y, w2.z, w2.w};
#pragma unroll
        for (int i = 0; i < 4; ++i)
#pragma unroll
          for (int j = 0; j < 4; ++j) {
            acc1[i][j] = fmaf(av[i], w1v[j], acc1[i][j]);
            acc2[i][j] = fmaf(av[i], w2v[j], acc2[i][j]);
          }
      }
      __syncthreads();
    }
#pragma unroll
    for (int i = 0; i < 4; ++i) {
      int row = bm + tm4 + i;
      float* yp = REV + (size_t)row * 300 + n0 + tn4;
#pragma unroll
      for (int j = 0; j < 4; ++j) {
        int col = n0 + tn4 + j;
        if (col < 300) {
          float a = acc1[i][j] + g1b[col];
          float b = acc2[i][j] + g2b[col];
          yp[j] = (1.f / (1.f + expf(-a))) * tanhf(b);
        }
      }
    }
  } else if (bid < 675) {
    int zi = bid - 600, z = zi / 25, r = zi % 25;
    gemm_tile<MODE_TN, false>(arena, Wur + (size_t)z * 90000, Mr + (size_t)z * 90000,
                              nullptr, Wp + (size_t)z * 90000, nullptr,
                              300, (r / 5) * 64, (r % 5) * 64, t);
  } else if (bid < 750) {
    int zi = bid - 675, z = zi / 25, r = zi % 25;
    gemm_tile<MODE_NN, false>(arena, Mw + (size_t)z * 90000, Wiw + (size_t)z * 90000,
                              nullptr, A1 + (size_t)z * 90000, nullptr,
                              300, (r / 5) * 64, (r % 5) * 64, t);
  } else if (bid < 762) {
    // t1s[z][e] = sum_k Mw[z][e,k] * biw[z][k]  (row-form, wave-shfl dots)
    int idx = bid - 750, z = idx >> 2, qb = idx & 3;
    const float* Mwz = Mw + (size_t)z * 90000;
    const float* bw = biw + z * 300;
    int w = t >> 6, j = t & 63;
    int e0 = qb * 75;
    for (int i = 0; i < 19; ++i) {
      int el = w + 4 * i;
      if (el < 75) {
        int e = e0 + el;
        float partial = 0.f;
#pragma unroll
        for (int c = 0; c < 5; ++c) {
          int k = j + c * 64;
          if (k < 300) partial = fmaf(Mwz[(size_t)e * 300 + k], bw[k], partial);
        }
#pragma unroll
        for (int m = 32; m >= 1; m >>= 1) partial += __shfl_xor(partial, m);
        if (j == 0) T1S[z * 300 + e] = partial;
      }
    }
  } else if (bid < 768) {
    // t2s[z][e] = sum_d Mw[z][d,e] * buw[z][d]  (column-form, ILP-15)
    int idx = bid - 762, z = idx >> 1, half = idx & 1;
    const float* Mwz = Mw + (size_t)z * 90000;
    float* vb = arena;
    for (int d = t; d < 300; d += 256) vb[d] = buw[z * 300 + d];
    __syncthreads();
    if (t < 150) {
      int e = half * 150 + t;
      float a = 0.f;
      for (int d0 = 0; d0 < 300; d0 += 15) {
        float mv[15];
#pragma unroll
        for (int q = 0; q < 15; ++q) mv[q] = Mwz[(size_t)(d0 + q) * 300 + e];
#pragma unroll
        for (int q = 0; q < 15; ++q) a = fmaf(mv[q], vb[d0 + q], a);
      }
      T2S[z * 300 + e] = a;
    }
  } else {
    // Bp[z][e] = sum_d Mr[z][d,e] * bur[z][d]  (ascending-d, bitwise kept)
    int idx = bid - 768, z = idx >> 1, half = idx & 1;
    const float* Mrz = Mr + (size_t)z * 90000;
    float* vb = arena;
    for (int d = t; d < 300; d += 256) vb[d] = bur[z * 300 + d];
    __syncthreads();
    if (t < 150) {
      int e = half * 150 + t;
      float a = 0.f;
      for (int d0 = 0; d0 < 300; d0 += 15) {
        float mv[15];
#pragma unroll
        for (int q = 0; q < 15; ++q) mv[q] = Mrz[(size_t)(d0 + q) * 300 + e];
#pragma unroll
        for (int q = 0; q < 15; ++q) a = fmaf(mv[q], vb[d0 + q], a);
      }
      Bp[z * 300 + e] = a;
    }
  }
}

// L3: TP/IP GEMMs (0..899, float4-staged) + KG (900..974) + stage-B (975..986).
__global__ __launch_bounds__(256)
void rev128_kernel(Ptr6 P, const float* __restrict__ Wuw,
                   const float* __restrict__ Wiw,
                   const float* __restrict__ A1,
                   float* __restrict__ KG, float* __restrict__ KGT,
                   const float* __restrict__ T1S, const float* __restrict__ T2S,
                   float* __restrict__ CGH) {
  __shared__ __align__(16) float arena[4080];  // 16320 B
  int bid = blockIdx.x, t = threadIdx.x;
  if (bid >= 975) {
    int idx = bid - 975;
    int z = idx >> 2;
    int r2 = idx & 3;
    int which = r2 >> 1, half = r2 & 1;
    const float* W = (which ? Wiw : Wuw) + (size_t)z * 90000;
    const float* tv = (which ? T2S : T1S) + z * 300;
    float* vb = arena;
    for (int d = t; d < 300; d += 256) vb[d] = tv[d];
    __syncthreads();
    if (t < 150) {
      int k = half * 150 + t;
      float a = 0.f;
      for (int d0 = 0; d0 < 300; d0 += 15) {
        float mv[15];
#pragma unroll
        for (int q = 0; q < 15; ++q) mv[q] = W[(size_t)(d0 + q) * 300 + k];
#pragma unroll
        for (int q = 0; q < 15; ++q) a = fmaf(mv[q], vb[d0 + q], a);
      }
      CGH[(size_t)(2 * z + which) * 300 + k] = a;
    }
    return;
  }
  if (bid >= 900) {
    int zi = bid - 900, z = zi / 25, r = zi % 25;
    gemm_tile<MODE_TN, false>(arena, Wuw + (size_t)z * 90000, A1 + (size_t)z * 90000,
                              nullptr, KG + (size_t)z * 90000,
                              KGT + (size_t)z * 90000,
                              300, (r / 5) * 64, (r % 5) * 64, t);
    return;
  }
  int z = bid / 150;
  int rem = bid - z * 150;
  int bm = (rem % 30) * 128;
  int n0 = (rem / 30) * 64;
  const bool nt = z >= 3;
  const float* __restrict__ X = P.X[z];
  const float* __restrict__ W = P.W[z];
  const float* __restrict__ bias = P.Bb[z];
  float* __restrict__ Y = P.Y[z];
  float (*Xs)[136] = (float(*)[136])arena;            // 20*136 = 2720
  float (*Ws_)[68] = (float(*)[68])(arena + 2720);    // 20*68  = 1360
  int tm8 = (t >> 4) * 8, tn4 = (t & 15) * 4;
  float acc[8][4] = {{0.f}};
  for (int k0 = 0; k0 < 300; k0 += 20) {
    // X panel: 128 rows x 5 float4 = 640
    for (int fid = t; fid < 640; fid += 256) {
      int row = fid / 5, q = fid - row * 5;
      float4 v = *(const float4*)&X[(size_t)(bm + row) * 300 + k0 + q * 4];
      int kq = q * 4;
      Xs[kq + 0][row] = v.x; Xs[kq + 1][row] = v.y;
      Xs[kq + 2][row] = v.z; Xs[kq + 3][row] = v.w;
    }
    // W panel: 320 float4
    if (nt) {
      for (int fid = t; fid < 320; fid += 256) {
        int dl = fid / 5, q = fid - dl * 5;
        int d = n0 + dl;
        float4 v = {0.f, 0.f, 0.f, 0.f};
        if (d < 300) v = *(const float4*)&W[(size_t)d * 300 + k0 + q * 4];
        int kq = q * 4;
        Ws_[kq + 0][dl] = v.x; Ws_[kq + 1][dl] = v.y;
        Ws_[kq + 2][dl] = v.z; Ws_[kq + 3][dl] = v.w;
      }
    } else {
      for (int fid = t; fid < 320; fid += 256) {
        int kk = fid >> 4, ng = fid & 15;
        int col = n0 + ng * 4;
        float4 v = {0.f, 0.f, 0.f, 0.f};
        if (col + 3 < 300) v = *(const float4*)&W[(size_t)(k0 + kk) * 300 + col];
        *(float4*)&Ws_[kk][ng * 4] = v;
      }
    }
    __syncthreads();
#pragma unroll
    for (int kk = 0; kk < 20; ++kk) {
      const float4 a0 = *(const float4*)&Xs[kk][tm8];
      const float4 a1 = *(const float4*)&Xs[kk][tm8 + 4];
      const float4 w = *(const float4*)&Ws_[kk][tn4];
      float av[8] = {a0.x, a0.y, a0.z, a0.w, a1.x, a1.y, a1.z, a1.w};
      float wv[4] = {w.x, w.y, w.z, w.w};
#pragma unroll
      for (int i = 0; i < 8; ++i)
#pragma unroll
        for (int j = 0; j < 4; ++j)
          acc[i][j] = fmaf(av[i], wv[j], acc[i][j]);
    }
    __syncthreads();
  }
  float bv[4];
#pragma unroll
  for (int j = 0; j < 4; ++j) {
    int col = n0 + tn4 + j;
    bv[j] = (col < 300) ? bias[col] : 0.f;
  }
#pragma unroll
  for (int i = 0; i < 8; ++i) {
    float* yp = Y + (size_t)(bm + tm8 + i) * 300 + n0 + tn4;
#pragma unroll
    for (int j = 0; j < 4; ++j) {
      int col = n0 + tn4 + j;
      if (col < 300) yp[j] = acc[i][j] + bv[j];
    }
  }
}

// L4: review scores (float4 dot) + gumbel-argmax + fused MEAN.
__global__ __launch_bounds__(256)
void argmax_mean_kernel(const float* __restrict__ Tall, const float* __restrict__ Iall,
                        const int* __restrict__ uRevs, const int* __restrict__ iRevs,
                        const float* __restrict__ uEmb, const float* __restrict__ iEmb,
                        int* __restrict__ idxU, int* __restrict__ idxI,
                        float* __restrict__ MEAN, GKeys K) {
  int b = blockIdx.x, z = blockIdx.y, t = threadIdx.x;
  uint32_t ku0 = K.v[z * 4], ku1 = K.v[z * 4 + 1];
  uint32_t ki0 = K.v[z * 4 + 2], ki1 = K.v[z * 4 + 3];
  __shared__ __align__(16) float Is[30 * 304];
  __shared__ float Sc[900];
  __shared__ float us[30], vs[30];
  __shared__ int selU, selI;
  __shared__ int toksI_s[60], toksU_s[60];
  const float* Tb = Tall + (size_t)z * 1152000 + (size_t)b * 9000;
  const float* Ib = Iall + (size_t)z * 1152000 + (size_t)b * 9000;
  for (int fc = t; fc < 2250; fc += 256) {
    int r = fc / 75, q = fc - r * 75;
    *(float4*)&Is[r * 304 + q * 4] = *(const float4*)&Ib[r * 300 + q * 4];
  }
  __syncthreads();
  for (int id = t; id < 900; id += 256) {
    int r = id / 30, c = id - r * 30;
    const float* tr = Tb + r * 300;
    const float* ic = Is + c * 304;
    float acc = 0.f;
    for (int k = 0; k < 300; k += 4) {
      float4 a = *(const float4*)&tr[k];
      float4 w = *(const float4*)&ic[k];
      acc = fmaf(a.x, w.x, acc);
      acc = fmaf(a.y, w.y, acc);
      acc = fmaf(a.z, w.z, acc);
      acc = fmaf(a.w, w.w, acc);
    }
    Sc[id] = acc;
  }
  __syncthreads();
  if (t < 30) {
    float m = -3.4e38f;
    for (int c = 0; c < 30; ++c) m = fmaxf(m, Sc[t * 30 + c]);
    us[t] = m + jax_gumbel32(ku0, ku1, (uint32_t)(b * 30 + t));
  } else if (t >= 64 && t < 94) {
    int s = t - 64;
    float m = -3.4e38f;
    for (int r = 0; r < 30; ++r) m = fmaxf(m, Sc[r * 30 + s]);
    vs[s] = m + jax_gumbel32(ki0, ki1, (uint32_t)(b * 30 + s));
  }
  __syncthreads();
  if (t == 0) {
    int best = 0; float bvv = us[0];
    for (int r = 1; r < 30; ++r) { if (us[r] > bvv) { bvv = us[r]; best = r; } }
    idxU[z * 128 + b] = best; selU = best;
  } else if (t == 1) {
    int best = 0; float bvv = vs[0];
    for (int s = 1; s < 30; ++s) { if (vs[s] > bvv) { bvv = vs[s]; best = s; } }
    idxI[z * 128 + b] = best; selI = best;
  }
  __syncthreads();
  if (t < 60) toksI_s[t] = iRevs[(b * 30 + selI) * 60 + t];
  else if (t >= 64 && t < 124) toksU_s[t - 64] = uRevs[(b * 30 + selU) * 60 + (t - 64)];
  __syncthreads();
  for (int dd = t; dd < 600; dd += 256) {
    int side = dd / 300;
    int d = dd - side * 300;
    const int* tk = side ? toksU_s : toksI_s;
    const float* em = side ? uEmb : iEmb;
    float acc = 0.f;
#pragma unroll
    for (int l0 = 0; l0 < 60; l0 += 10) {
      float v[10];
#pragma unroll
      for (int q = 0; q < 10; ++q)
        v[q] = em[(size_t)tk[l0 + q] * 300 + d];
#pragma unroll
      for (int q = 0; q < 10; ++q) acc += v[q];
    }
    MEAN[((size_t)(2 * z + side) * 128 + b) * 300 + d] = acc * (1.f / 60.f);
  }
}

// L5: per (b, side, p): gv = MEAN@K + c (fused); scores; softmax; weighted sum.
__global__ __launch_bounds__(256)
void word_rep_kernel(const int* __restrict__ uRevs, const int* __restrict__ iRevs,
                     const float* __restrict__ uEmb, const float* __restrict__ iEmb,
                     const int* __restrict__ idxU, const int* __restrict__ idxI,
                     const float* __restrict__ MEAN, const float* __restrict__ KG,
                     const float* __restrict__ KGT, const float* __restrict__ CGH,
                     float* __restrict__ JNT) {
  int b = blockIdx.x, side = blockIdx.y, p = blockIdx.z;
  int zz = 2 * p + side;
  const int* revs = side ? iRevs : uRevs;
  const float* emb = side ? iEmb : uEmb;
  int idx = side ? idxI[p * 128 + b] : idxU[p * 128 + b];
  const float* Kmat = (side ? KGT : KG) + (size_t)p * 90000;
  __shared__ int toks[60];
  __shared__ float ms[300];
  __shared__ float g_s[300];
  __shared__ float score[60];
  __shared__ float probs[64];
  int t = threadIdx.x;
  if (t < 60) toks[t] = revs[(b * 30 + idx) * 60 + t];
  const float* mrow = MEAN + ((size_t)zz * 128 + b) * 300;
  for (int d = t; d < 300; d += 256) ms[d] = mrow[d];
  __syncthreads();
  for (int k = t; k < 300; k += 256) {
    const float* kr = Kmat + (size_t)k * 300;
    float acc = 0.f;
    for (int e = 0; e < 300; e += 4) {
      float4 kv = *(const float4*)&kr[e];
      acc = fmaf(kv.x, ms[e], acc);
      acc = fmaf(kv.y, ms[e + 1], acc);
      acc = fmaf(kv.z, ms[e + 2], acc);
      acc = fmaf(kv.w, ms[e + 3], acc);
    }
    g_s[k] = acc + CGH[(size_t)zz * 300 + k];
  }
  __syncthreads();
  int w = t >> 6, j = t & 63;
  for (int i = 0; i < 15; ++i) {
    int l = w * 15 + i;
    const float* er = emb + (size_t)toks[l] * 300;
    float partial = 0.f;
#pragma unroll
    for (int c = 0; c < 5; ++c) {
      int k = j + c * 64;
      if (k < 300) partial = fmaf(er[k], g_s[k], partial);
    }
#pragma unroll
    for (int m = 32; m >= 1; m >>= 1) partial += __shfl_xor(partial, m);
    if (j == 0) score[l] = partial;
  }
  __syncthreads();
  if (w == 0) {
    float s = (j < 60) ? score[j] : -3.4e38f;
    float m = s;
#pragma unroll
    for (int mm = 32; mm >= 1; mm >>= 1) m = fmaxf(m, __shfl_xor(m, mm));
    float e = (j < 60) ? expf(s - m) : 0.f;
    float sum = e;
#pragma unroll
    for (int mm = 32; mm >= 1; mm >>= 1) sum += __shfl_xor(sum, mm);
    if (j < 60) probs[j] = e / sum;
  }
  __syncthreads();
  float* outp = JNT + (size_t)b * 1800 + side * 900 + p * 300;
  for (int d = t; d < 300; d += 256) {
    float acc = 0.f;
    for (int l0 = 0; l0 < 60; l0 += 6) {
      float e0 = emb[(size_t)toks[l0 + 0] * 300 + d];
      float e1 = emb[(size_t)toks[l0 + 1] * 300 + d];
      float e2 = emb[(size_t)toks[l0 + 2] * 300 + d];
      float e3 = emb[(size_t)toks[l0 + 3] * 300 + d];
      float e4 = emb[(size_t)toks[l0 + 4] * 300 + d];
      float e5 = emb[(size_t)toks[l0 + 5] * 300 + d];
      acc = fmaf(probs[l0 + 0], e0, acc);
      acc = fmaf(probs[l0 + 1], e1, acc);
      acc = fmaf(probs[l0 + 2], e2, acc);
      acc = fmaf(probs[l0 + 3], e3, acc);
      acc = fmaf(probs[l0 + 4], e4, acc);
      acc = fmaf(probs[l0 + 5], e5, acc);
    }
    outp[d] = acc;
  }
}

// L6: factorization machine.
__global__ __launch_bounds__(64)
void fm_kernel(const float* __restrict__ JNT, const float* __restrict__ w0,
               const float* __restrict__ fw, const float* __restrict__ fv,
               float* __restrict__ out) {
  int b = blockIdx.x, lane = threadIdx.x;
  const float* x = JNT + (size_t)b * 1800;
  float lin = 0.f;
  float t1[10], t2[10];
#pragma unroll
  for (int k = 0; k < 10; ++k) { t1[k] = 0.f; t2[k] = 0.f; }
  for (int j = lane; j < 1800; j += 64) {
    float xv = x[j];
    lin = fmaf(fw[j], xv, lin);
    float xx = xv * xv;
#pragma unroll
    for (int k = 0; k < 10; ++k) {
      float v = fv[j * 10 + k];
      t1[k] = fmaf(xv, v, t1[k]);
      t2[k] = fmaf(xx, v * v, t2[k]);
    }
  }
#pragma unroll
  for (int m = 32; m >= 1; m >>= 1) {
    lin += __shfl_xor(lin, m);
#pragma unroll
    for (int k = 0; k < 10; ++k) {
      t1[k] += __shfl_xor(t1[k], m);
      t2[k] += __shfl_xor(t2[k], m);
    }
  }
  if (lane == 0) {
    float inter = 0.f;
#pragma unroll
    for (int k = 0; k < 10; ++k) inter += t1[k] * t1[k] - t2[k];
    out[b] = w0[0] + lin + 0.5f * inter;
  }
}

extern "C" void kernel_launch(void* const* d_in, const int* in_sizes, int n_in,
                              void* d_out, int out_size, void* d_ws, size_t ws_size,
                              hipStream_t stream) {
  (void)in_sizes; (void)n_in; (void)out_size;
  const int*   uRevs = (const int*)d_in[0];
  const int*   iRevs = (const int*)d_in[1];
  const float* uEmb  = (const float*)d_in[2];
  const float* iEmb  = (const float*)d_in[3];
  const float* g1w   = (const float*)d_in[4];
  const float* g1b   = (const float*)d_in[5];
  const float* g2w   = (const float*)d_in[6];
  const float* g2b   = (const float*)d_in[7];
  const float* Mr    = (const float*)d_in[8];
  const float* Wur   = (const float*)d_in[9];
  const float* bur   = (const float*)d_in[10];
  const float* Wir   = (const float*)d_in[11];
  const float* bir   = (const float*)d_in[12];
  const float* Mw    = (const float*)d_in[13];
  const float* Wuw   = (const float*)d_in[14];
  const float* buw   = (const float*)d_in[15];
  const float* Wiw   = (const float*)d_in[16];
  const float* biw   = (const float*)d_in[17];
  const float* fmw0  = (const float*)d_in[18];
  const float* fmw   = (const float*)d_in[19];
  const float* fmv   = (const float*)d_in[20];
  float* out = (float*)d_out;

  float* ws = (float*)d_ws;
  const size_t NEED_BYTES = (size_t)10300500 * 4;
  if (ws_size < NEED_BYTES) return;

  float* S     = ws + 0;
  float* TPall = ws + 0;
  float* REV   = ws + 3456000;
  float* MEAN  = ws + 3456000;
  float* JNT   = ws + 3916800;
  int*   idxU  = (int*)(ws + 4147200);
  int*   idxI  = idxU + 384;
  float* IPall = ws + 5760000;
  float* A1    = ws + 9216000;
  float* Wp    = ws + 9486000;
  float* KG    = ws + 9756000;
  float* KGT   = ws + 10026000;
  float* Bp    = ws + 10296000;
  float* CGH   = ws + 10296900;
  float* T1S   = ws + 10298700;
  float* T2S   = ws + 10299600;

  // L1: gather-sum
  gather_kernel<<<dim3(1920), dim3(320), 0, stream>>>(
      uRevs, iRevs, uEmb, iEmb, S);

  // L2: review gate + Wp + A1 + stage-A bias pieces
  gate_kernel<<<dim3(774), dim3(256), 0, stream>>>(
      S, g1w, g1b, g2w, g2b, REV,
      Wur, Mr, Mw, Wiw, bur, buw, biw, Wp, A1, T1S, T2S, Bp);

  // L3: TP/IP GEMMs + KG (+KGT) + stage-B bias (CGH)
  {
    Ptr6 P;
    for (int z = 0; z < 3; ++z) {
      P.X[z] = REV;
      P.W[z] = Wp + (size_t)z * 90000;
      P.Bb[z] = Bp + z * 300;
      P.Y[z] = TPall + (size_t)z * 1152000;
      P.X[z + 3] = REV + (size_t)3840 * 300;
      P.W[z + 3] = Wir + (size_t)z * 90000;
      P.Bb[z + 3] = bir + z * 300;
      P.Y[z + 3] = IPall + (size_t)z * 1152000;
    }
    rev128_kernel<<<dim3(987), dim3(256), 0, stream>>>(
        P, Wuw, Wiw, A1, KG, KGT, T1S, T2S, CGH);
  }

  // L4: gumbel-argmax + fused MEAN
  {
    GKeys K;
    for (int p = 0; p < 3; ++p) {
      tf2x32(0u, 42u, 0u, (uint32_t)(2 * p),     &K.v[p * 4],     &K.v[p * 4 + 1]);
      tf2x32(0u, 42u, 0u, (uint32_t)(2 * p + 1), &K.v[p * 4 + 2], &K.v[p * 4 + 3]);
    }
    argmax_mean_kernel<<<dim3(128, 3), dim3(256), 0, stream>>>(
        TPall, IPall, uRevs, iRevs, uEmb, iEmb, idxU, idxI, MEAN, K);
  }

  // L5: word-level reps (gv matvec fused in)
  word_rep_kernel<<<dim3(128, 2, 3), dim3(256), 0, stream>>>(
      uRevs, iRevs, uEmb, iEmb, idxU, idxI, MEAN, KG, KGT, CGH, JNT);

  // L6: factorization machine
  fm_kernel<<<dim3(128), dim3(64), 0, stream>>>(JNT, fmw0, fmw, fmv, out);
}

// Round 13
// 330.805 us; speedup vs baseline: 1.2177x; 1.0093x over previous
//
#include <hip/hip_runtime.h>
#include <stdint.h>
#include <math.h>

// ---------------------------------------------------------------------------
// MPCN (B=128, R=30, L=60, D=300, V=50000, P=3), f32 end-to-end.
// Round 13: r12 + bank-conflict-free staging lane-maps (row-minor fid
// mapping: wave covers 64 distinct rows at same q -> 2-way writes, free).
// LDS contents identical -> bitwise-neutral -> selections frozen.
// ---------------------------------------------------------------------------

__host__ __device__ static inline void tf2x32(uint32_t k0, uint32_t k1,
                                              uint32_t x0, uint32_t x1,
                                              uint32_t* o0, uint32_t* o1) {
  uint32_t ks[3] = {k0, k1, k0 ^ k1 ^ 0x1BD11BDAu};
  x0 += ks[0]; x1 += ks[1];
  const int rotA[4] = {13, 15, 26, 6};
  const int rotB[4] = {17, 29, 16, 24};
#pragma unroll
  for (int i = 0; i < 5; ++i) {
    const int* rot = ((i & 1) == 0) ? rotA : rotB;
#pragma unroll
    for (int j = 0; j < 4; ++j) {
      x0 += x1;
      x1 = (x1 << rot[j]) | (x1 >> (32 - rot[j]));
      x1 ^= x0;
    }
    x0 += ks[(i + 1) % 3];
    x1 += ks[(i + 2) % 3] + (uint32_t)(i + 1);
  }
  *o0 = x0; *o1 = x1;
}

struct GKeys { uint32_t v[12]; };
struct Ptr6 {
  const float* X[6];
  const float* W[6];
  const float* Bb[6];
  float*       Y[6];
};

__device__ static inline float jax_gumbel32(uint32_t k0, uint32_t k1, uint32_t idx) {
  uint32_t o0, o1;
  tf2x32(k0, k1, 0u, idx, &o0, &o1);
  uint32_t bits = o0 ^ o1;
  float f = __uint_as_float((bits >> 9) | 0x3f800000u) - 1.0f;
  float u = (f > 0.0f) ? f : 1.17549435e-38f;
  return -logf(-logf(u));
}

#define MODE_NN 0
#define MODE_NT 1
#define MODE_TN 2

// 64x64 f32 GEMM tile, K=N=300, ld=300, caller-provided LDS arena
// (needs 2*20*68 = 2720 floats). Optional transposed second output Yt.
template <int MODE, bool BIAS>
__device__ __forceinline__ void gemm_tile(float* __restrict__ sm,
                                          const float* __restrict__ X,
                                          const float* __restrict__ W,
                                          const float* __restrict__ bias,
                                          float* __restrict__ Y,
                                          float* __restrict__ Yt,
                                          int M, int bm, int n0, int t) {
  float (*Xs)[68] = (float(*)[68])sm;
  float (*Ws_)[68] = (float(*)[68])(sm + 20 * 68);
  const bool act = t < 256;
  int tm4 = ((t >> 4) & 15) * 4;
  int tn4 = (t & 15) * 4;
  float acc[4][4] = {{0.f}};
  int xm = t >> 2;
  int xk = (t & 3) * 5;
  for (int k0 = 0; k0 < 300; k0 += 20) {
    if (act) {
      if (MODE == MODE_TN) {
#pragma unroll
        for (int i = 0; i < 5; ++i) {
          int flat = t + i * 256;
          int kk = flat >> 6, nn = flat & 63;
          int r = bm + nn;
          Xs[kk][nn] = (r < 300) ? X[(size_t)(k0 + kk) * 300 + r] : 0.f;
        }
      } else {
        int rr = bm + xm; if (rr >= M) rr = M - 1;
        const float* xp = X + (size_t)rr * 300 + k0 + xk;
#pragma unroll
        for (int j = 0; j < 5; ++j) Xs[xk + j][xm] = xp[j];
      }
      if (MODE == MODE_NT) {
        int d = n0 + xm;
        bool ok = d < 300;
        const float* wp = W + (size_t)d * 300 + k0 + xk;
#pragma unroll
        for (int j = 0; j < 5; ++j) Ws_[xk + j][xm] = ok ? wp[j] : 0.f;
      } else {
#pragma unroll
        for (int i = 0; i < 5; ++i) {
          int flat = t + i * 256;
          int kk = flat >> 6, nn = flat & 63;
          int col = n0 + nn;
          Ws_[kk][nn] = (col < 300) ? W[(size_t)(k0 + kk) * 300 + col] : 0.f;
        }
      }
    }
    __syncthreads();
    if (act) {
#pragma unroll
      for (int kk = 0; kk < 20; ++kk) {
        const float4 a = *(const float4*)&Xs[kk][tm4];
        const float4 w = *(const float4*)&Ws_[kk][tn4];
        float av[4] = {a.x, a.y, a.z, a.w};
        float wv[4] = {w.x, w.y, w.z, w.w};
#pragma unroll
        for (int i = 0; i < 4; ++i)
#pragma unroll
          for (int j = 0; j < 4; ++j)
            acc[i][j] = fmaf(av[i], wv[j], acc[i][j]);
      }
    }
    __syncthreads();
  }
  if (!act) return;
  float bv[4] = {0.f, 0.f, 0.f, 0.f};
  if (BIAS) {
#pragma unroll
    for (int j = 0; j < 4; ++j) {
      int col = n0 + tn4 + j;
      if (col < 300) bv[j] = bias[col];
    }
  }
#pragma unroll
  for (int i = 0; i < 4; ++i) {
    int row = bm + tm4 + i;
    if (row < M) {
      float* yp = Y + (size_t)row * 300 + n0 + tn4;
#pragma unroll
      for (int j = 0; j < 4; ++j) {
        int col = n0 + tn4 + j;
        if (col < 300) yp[j] = acc[i][j] + bv[j];
      }
    }
  }
  if (Yt) {
#pragma unroll
    for (int i = 0; i < 4; ++i) {
      int row = bm + tm4 + i;
      if (row < 300) {
#pragma unroll
        for (int j = 0; j < 4; ++j) {
          int col = n0 + tn4 + j;
          if (col < 300) Yt[(size_t)col * 300 + row] = acc[i][j];
        }
      }
    }
  }
}

// L1: gather-sum, minimal-resource, 15-deep ILP (ascending-l adds).
__global__ __launch_bounds__(320)
void gather_kernel(const int* __restrict__ uRevs, const int* __restrict__ iRevs,
                   const float* __restrict__ uEmb, const float* __restrict__ iEmb,
                   float* __restrict__ S) {
  int bid = blockIdx.x;   // 0..1919
  int t = threadIdx.x;
  __shared__ int toks[4][60];
  if (t < 240) {
    int rr = t / 60, l = t - rr * 60;
    int grow = bid * 4 + rr;
    int side = grow / 3840;
    int row = grow - side * 3840;
    const int* revs = side ? iRevs : uRevs;
    toks[rr][l] = revs[row * 60 + l];
  }
  __syncthreads();
  if (t < 300) {
    int sub = t / 75;
    int q4 = (t - sub * 75) * 4;
    int grow = bid * 4 + sub;
    int side = grow / 3840;
    const float* emb = side ? iEmb : uEmb;
    const int* tk = toks[sub];
    float ax = 0.f, ay = 0.f, az = 0.f, aw = 0.f;
#pragma unroll
    for (int l0 = 0; l0 < 60; l0 += 15) {
      float4 v[15];
#pragma unroll
      for (int qq = 0; qq < 15; ++qq)
        v[qq] = *(const float4*)&emb[(size_t)tk[l0 + qq] * 300 + q4];
#pragma unroll
      for (int qq = 0; qq < 15; ++qq) {
        ax += v[qq].x; ay += v[qq].y; az += v[qq].z; aw += v[qq].w;
      }
    }
    float4 r = {ax, ay, az, aw};
    *(float4*)&S[(size_t)grow * 300 + q4] = r;
  }
}

// L2: review gate (0..599, conflict-free float4 staging) + Wp (600..674) +
// A1 (675..749) + stage-A bias pieces (750..773).
__global__ __launch_bounds__(256)
void gate_kernel(const float* __restrict__ S,
                 const float* __restrict__ g1w, const float* __restrict__ g1b,
                 const float* __restrict__ g2w, const float* __restrict__ g2b,
                 float* __restrict__ REV,
                 const float* __restrict__ Wur, const float* __restrict__ Mr,
                 const float* __restrict__ Mw, const float* __restrict__ Wiw,
                 const float* __restrict__ bur, const float* __restrict__ buw,
                 const float* __restrict__ biw,
                 float* __restrict__ Wp, float* __restrict__ A1,
                 float* __restrict__ T1S, float* __restrict__ T2S,
                 float* __restrict__ Bp) {
  __shared__ __align__(16) float arena[4080];  // 16320 B
  int bid = blockIdx.x, t = threadIdx.x;
  if (bid < 600) {
    float (*Xs)[68] = (float(*)[68])arena;
    float (*Ws1)[68] = (float(*)[68])(arena + 1360);
    float (*Ws2)[68] = (float(*)[68])(arena + 2720);
    int bm = (bid / 5) * 64;
    int n0 = (bid % 5) * 64;
    int tm4 = (t >> 4) * 4;
    int tn4 = (t & 15) * 4;
    float acc1[4][4] = {{0.f}};
    float acc2[4][4] = {{0.f}};
    for (int k0 = 0; k0 < 300; k0 += 20) {
      // X panel: 320 float4 = 64 rows x 5 q; row-minor map (row = fid&63)
      for (int fid = t; fid < 320; fid += 256) {
        int row = fid & 63, q = fid >> 6;
        float4 v = *(const float4*)&S[(size_t)(bm + row) * 300 + k0 + q * 4];
        int kq = q * 4;
        Xs[kq + 0][row] = v.x; Xs[kq + 1][row] = v.y;
        Xs[kq + 2][row] = v.z; Xs[kq + 3][row] = v.w;
      }
      // W1 panel (NT, zero-fill d>=300)
      for (int fid = t; fid < 320; fid += 256) {
        int dl = fid & 63, q = fid >> 6;
        int d = n0 + dl;
        float4 v = {0.f, 0.f, 0.f, 0.f};
        if (d < 300) v = *(const float4*)&g1w[(size_t)d * 300 + k0 + q * 4];
        int kq = q * 4;
        Ws1[kq + 0][dl] = v.x; Ws1[kq + 1][dl] = v.y;
        Ws1[kq + 2][dl] = v.z; Ws1[kq + 3][dl] = v.w;
      }
      // W2 panel
      for (int fid = t; fid < 320; fid += 256) {
        int dl = fid & 63, q = fid >> 6;
        int d = n0 + dl;
        float4 v = {0.f, 0.f, 0.f, 0.f};
        if (d < 300) v = *(const float4*)&g2w[(size_t)d * 300 + k0 + q * 4];
        int kq = q * 4;
        Ws2[kq + 0][dl] = v.x; Ws2[kq + 1][dl] = v.y;
        Ws2[kq + 2][dl] = v.z; Ws2[kq + 3][dl] = v.w;
      }
      __syncthreads();
#pragma unroll
      for (int kk = 0; kk < 20; ++kk) {
        const float4 a = *(const float4*)&Xs[kk][tm4];
        const float4 w1 = *(const float4*)&Ws1[kk][tn4];
        const float4 w2 = *(const float4*)&Ws2[kk][tn4];
        float av[4] = {a.x, a.y, a.z, a.w};
        float w1v[4] = {w1.x, w1.y, w1.z, w1.w};
        float w2v[4] = {w2.x, w2.y, w2.z, w2.w};
#pragma unroll
        for (int i = 0; i < 4; ++i)
#pragma unroll
          for (int j = 0; j < 4; ++j) {
            acc1[i][j] = fmaf(av[i], w1v[j], acc1[i][j]);
            acc2[i][j] = fmaf(av[i], w2v[j], acc2[i][j]);
          }
      }
      __syncthreads();
    }
#pragma unroll
    for (int i = 0; i < 4; ++i) {
      int row = bm + tm4 + i;
      float* yp = REV + (size_t)row * 300 + n0 + tn4;
#pragma unroll
      for (int j = 0; j < 4; ++j) {
        int col = n0 + tn4 + j;
        if (col < 300) {
          float a = acc1[i][j] + g1b[col];
          float b = acc2[i][j] + g2b[col];
          yp[j] = (1.f / (1.f + expf(-a))) * tanhf(b);
        }
      }
    }
  } else if (bid < 675) {
    int zi = bid - 600, z = zi / 25, r = zi % 25;
    gemm_tile<MODE_TN, false>(arena, Wur + (size_t)z * 90000, Mr + (size_t)z * 90000,
                              nullptr, Wp + (size_t)z * 90000, nullptr,
                              300, (r / 5) * 64, (r % 5) * 64, t);
  } else if (bid < 750) {
    int zi = bid - 675, z = zi / 25, r = zi % 25;
    gemm_tile<MODE_NN, false>(arena, Mw + (size_t)z * 90000, Wiw + (size_t)z * 90000,
                              nullptr, A1 + (size_t)z * 90000, nullptr,
                              300, (r / 5) * 64, (r % 5) * 64, t);
  } else if (bid < 762) {
    // t1s[z][e] = sum_k Mw[z][e,k] * biw[z][k]  (row-form, wave-shfl dots)
    int idx = bid - 750, z = idx >> 2, qb = idx & 3;
    const float* Mwz = Mw + (size_t)z * 90000;
    const float* bw = biw + z * 300;
    int w = t >> 6, j = t & 63;
    int e0 = qb * 75;
    for (int i = 0; i < 19; ++i) {
      int el = w + 4 * i;
      if (el < 75) {
        int e = e0 + el;
        float partial = 0.f;
#pragma unroll
        for (int c = 0; c < 5; ++c) {
          int k = j + c * 64;
          if (k < 300) partial = fmaf(Mwz[(size_t)e * 300 + k], bw[k], partial);
        }
#pragma unroll
        for (int m = 32; m >= 1; m >>= 1) partial += __shfl_xor(partial, m);
        if (j == 0) T1S[z * 300 + e] = partial;
      }
    }
  } else if (bid < 768) {
    // t2s[z][e] = sum_d Mw[z][d,e] * buw[z][d]  (column-form, ILP-15)
    int idx = bid - 762, z = idx >> 1, half = idx & 1;
    const float* Mwz = Mw + (size_t)z * 90000;
    float* vb = arena;
    for (int d = t; d < 300; d += 256) vb[d] = buw[z * 300 + d];
    __syncthreads();
    if (t < 150) {
      int e = half * 150 + t;
      float a = 0.f;
      for (int d0 = 0; d0 < 300; d0 += 15) {
        float mv[15];
#pragma unroll
        for (int q = 0; q < 15; ++q) mv[q] = Mwz[(size_t)(d0 + q) * 300 + e];
#pragma unroll
        for (int q = 0; q < 15; ++q) a = fmaf(mv[q], vb[d0 + q], a);
      }
      T2S[z * 300 + e] = a;
    }
  } else {
    // Bp[z][e] = sum_d Mr[z][d,e] * bur[z][d]  (ascending-d, bitwise kept)
    int idx = bid - 768, z = idx >> 1, half = idx & 1;
    const float* Mrz = Mr + (size_t)z * 90000;
    float* vb = arena;
    for (int d = t; d < 300; d += 256) vb[d] = bur[z * 300 + d];
    __syncthreads();
    if (t < 150) {
      int e = half * 150 + t;
      float a = 0.f;
      for (int d0 = 0; d0 < 300; d0 += 15) {
        float mv[15];
#pragma unroll
        for (int q = 0; q < 15; ++q) mv[q] = Mrz[(size_t)(d0 + q) * 300 + e];
#pragma unroll
        for (int q = 0; q < 15; ++q) a = fmaf(mv[q], vb[d0 + q], a);
      }
      Bp[z * 300 + e] = a;
    }
  }
}

// L3: TP/IP GEMMs (0..899, conflict-free float4 staging) + KG (900..974) +
// stage-B (975..986).
__global__ __launch_bounds__(256)
void rev128_kernel(Ptr6 P, const float* __restrict__ Wuw,
                   const float* __restrict__ Wiw,
                   const float* __restrict__ A1,
                   float* __restrict__ KG, float* __restrict__ KGT,
                   const float* __restrict__ T1S, const float* __restrict__ T2S,
                   float* __restrict__ CGH) {
  __shared__ __align__(16) float arena[4080];  // 16320 B
  int bid = blockIdx.x, t = threadIdx.x;
  if (bid >= 975) {
    int idx = bid - 975;
    int z = idx >> 2;
    int r2 = idx & 3;
    int which = r2 >> 1, half = r2 & 1;
    const float* W = (which ? Wiw : Wuw) + (size_t)z * 90000;
    const float* tv = (which ? T2S : T1S) + z * 300;
    float* vb = arena;
    for (int d = t; d < 300; d += 256) vb[d] = tv[d];
    __syncthreads();
    if (t < 150) {
      int k = half * 150 + t;
      float a = 0.f;
      for (int d0 = 0; d0 < 300; d0 += 15) {
        float mv[15];
#pragma unroll
        for (int q = 0; q < 15; ++q) mv[q] = W[(size_t)(d0 + q) * 300 + k];
#pragma unroll
        for (int q = 0; q < 15; ++q) a = fmaf(mv[q], vb[d0 + q], a);
      }
      CGH[(size_t)(2 * z + which) * 300 + k] = a;
    }
    return;
  }
  if (bid >= 900) {
    int zi = bid - 900, z = zi / 25, r = zi % 25;
    gemm_tile<MODE_TN, false>(arena, Wuw + (size_t)z * 90000, A1 + (size_t)z * 90000,
                              nullptr, KG + (size_t)z * 90000,
                              KGT + (size_t)z * 90000,
                              300, (r / 5) * 64, (r % 5) * 64, t);
    return;
  }
  int z = bid / 150;
  int rem = bid - z * 150;
  int bm = (rem % 30) * 128;
  int n0 = (rem / 30) * 64;
  const bool nt = z >= 3;
  const float* __restrict__ X = P.X[z];
  const float* __restrict__ W = P.W[z];
  const float* __restrict__ bias = P.Bb[z];
  float* __restrict__ Y = P.Y[z];
  float (*Xs)[136] = (float(*)[136])arena;            // 20*136 = 2720
  float (*Ws_)[68] = (float(*)[68])(arena + 2720);    // 20*68  = 1360
  int tm8 = (t >> 4) * 8, tn4 = (t & 15) * 4;
  float acc[8][4] = {{0.f}};
  for (int k0 = 0; k0 < 300; k0 += 20) {
    // X panel: 640 float4 = 128 rows x 5 q; row-minor map (row = fid&127)
    for (int fid = t; fid < 640; fid += 256) {
      int row = fid & 127, q = fid >> 7;
      float4 v = *(const float4*)&X[(size_t)(bm + row) * 300 + k0 + q * 4];
      int kq = q * 4;
      Xs[kq + 0][row] = v.x; Xs[kq + 1][row] = v.y;
      Xs[kq + 2][row] = v.z; Xs[kq + 3][row] = v.w;
    }
    // W panel: 320 float4
    if (nt) {
      for (int fid = t; fid < 320; fid += 256) {
        int dl = fid & 63, q = fid >> 6;
        int d = n0 + dl;
        float4 v = {0.f, 0.f, 0.f, 0.f};
        if (d < 300) v = *(const float4*)&W[(size_t)d * 300 + k0 + q * 4];
        int kq = q * 4;
        Ws_[kq + 0][dl] = v.x; Ws_[kq + 1][dl] = v.y;
        Ws_[kq + 2][dl] = v.z; Ws_[kq + 3][dl] = v.w;
      }
    } else {
      for (int fid = t; fid < 320; fid += 256) {
        int kk = fid >> 4, ng = fid & 15;
        int col = n0 + ng * 4;
        float4 v = {0.f, 0.f, 0.f, 0.f};
        if (col + 3 < 300) v = *(const float4*)&W[(size_t)(k0 + kk) * 300 + col];
        *(float4*)&Ws_[kk][ng * 4] = v;
      }
    }
    __syncthreads();
#pragma unroll
    for (int kk = 0; kk < 20; ++kk) {
      const float4 a0 = *(const float4*)&Xs[kk][tm8];
      const float4 a1 = *(const float4*)&Xs[kk][tm8 + 4];
      const float4 w = *(const float4*)&Ws_[kk][tn4];
      float av[8] = {a0.x, a0.y, a0.z, a0.w, a1.x, a1.y, a1.z, a1.w};
      float wv[4] = {w.x, w.y, w.z, w.w};
#pragma unroll
      for (int i = 0; i < 8; ++i)
#pragma unroll
        for (int j = 0; j < 4; ++j)
          acc[i][j] = fmaf(av[i], wv[j], acc[i][j]);
    }
    __syncthreads();
  }
  float bv[4];
#pragma unroll
  for (int j = 0; j < 4; ++j) {
    int col = n0 + tn4 + j;
    bv[j] = (col < 300) ? bias[col] : 0.f;
  }
#pragma unroll
  for (int i = 0; i < 8; ++i) {
    float* yp = Y + (size_t)(bm + tm8 + i) * 300 + n0 + tn4;
#pragma unroll
    for (int j = 0; j < 4; ++j) {
      int col = n0 + tn4 + j;
      if (col < 300) yp[j] = acc[i][j] + bv[j];
    }
  }
}

// L4: review scores (float4 dot) + gumbel-argmax + fused MEAN.
__global__ __launch_bounds__(256)
void argmax_mean_kernel(const float* __restrict__ Tall, const float* __restrict__ Iall,
                        const int* __restrict__ uRevs, const int* __restrict__ iRevs,
                        const float* __restrict__ uEmb, const float* __restrict__ iEmb,
                        int* __restrict__ idxU, int* __restrict__ idxI,
                        float* __restrict__ MEAN, GKeys K) {
  int b = blockIdx.x, z = blockIdx.y, t = threadIdx.x;
  uint32_t ku0 = K.v[z * 4], ku1 = K.v[z * 4 + 1];
  uint32_t ki0 = K.v[z * 4 + 2], ki1 = K.v[z * 4 + 3];
  __shared__ __align__(16) float Is[30 * 304];
  __shared__ float Sc[900];
  __shared__ float us[30], vs[30];
  __shared__ int selU, selI;
  __shared__ int toksI_s[60], toksU_s[60];
  const float* Tb = Tall + (size_t)z * 1152000 + (size_t)b * 9000;
  const float* Ib = Iall + (size_t)z * 1152000 + (size_t)b * 9000;
  for (int fc = t; fc < 2250; fc += 256) {
    int r = fc / 75, q = fc - r * 75;
    *(float4*)&Is[r * 304 + q * 4] = *(const float4*)&Ib[r * 300 + q * 4];
  }
  __syncthreads();
  for (int id = t; id < 900; id += 256) {
    int r = id / 30, c = id - r * 30;
    const float* tr = Tb + r * 300;
    const float* ic = Is + c * 304;
    float acc = 0.f;
    for (int k = 0; k < 300; k += 4) {
      float4 a = *(const float4*)&tr[k];
      float4 w = *(const float4*)&ic[k];
      acc = fmaf(a.x, w.x, acc);
      acc = fmaf(a.y, w.y, acc);
      acc = fmaf(a.z, w.z, acc);
      acc = fmaf(a.w, w.w, acc);
    }
    Sc[id] = acc;
  }
  __syncthreads();
  if (t < 30) {
    float m = -3.4e38f;
    for (int c = 0; c < 30; ++c) m = fmaxf(m, Sc[t * 30 + c]);
    us[t] = m + jax_gumbel32(ku0, ku1, (uint32_t)(b * 30 + t));
  } else if (t >= 64 && t < 94) {
    int s = t - 64;
    float m = -3.4e38f;
    for (int r = 0; r < 30; ++r) m = fmaxf(m, Sc[r * 30 + s]);
    vs[s] = m + jax_gumbel32(ki0, ki1, (uint32_t)(b * 30 + s));
  }
  __syncthreads();
  if (t == 0) {
    int best = 0; float bvv = us[0];
    for (int r = 1; r < 30; ++r) { if (us[r] > bvv) { bvv = us[r]; best = r; } }
    idxU[z * 128 + b] = best; selU = best;
  } else if (t == 1) {
    int best = 0; float bvv = vs[0];
    for (int s = 1; s < 30; ++s) { if (vs[s] > bvv) { bvv = vs[s]; best = s; } }
    idxI[z * 128 + b] = best; selI = best;
  }
  __syncthreads();
  if (t < 60) toksI_s[t] = iRevs[(b * 30 + selI) * 60 + t];
  else if (t >= 64 && t < 124) toksU_s[t - 64] = uRevs[(b * 30 + selU) * 60 + (t - 64)];
  __syncthreads();
  for (int dd = t; dd < 600; dd += 256) {
    int side = dd / 300;
    int d = dd - side * 300;
    const int* tk = side ? toksU_s : toksI_s;
    const float* em = side ? uEmb : iEmb;
    float acc = 0.f;
#pragma unroll
    for (int l0 = 0; l0 < 60; l0 += 10) {
      float v[10];
#pragma unroll
      for (int q = 0; q < 10; ++q)
        v[q] = em[(size_t)tk[l0 + q] * 300 + d];
#pragma unroll
      for (int q = 0; q < 10; ++q) acc += v[q];
    }
    MEAN[((size_t)(2 * z + side) * 128 + b) * 300 + d] = acc * (1.f / 60.f);
  }
}

// L5: per (b, side, p): gv = MEAN@K + c (fused); scores; softmax; weighted sum.
__global__ __launch_bounds__(256)
void word_rep_kernel(const int* __restrict__ uRevs, const int* __restrict__ iRevs,
                     const float* __restrict__ uEmb, const float* __restrict__ iEmb,
                     const int* __restrict__ idxU, const int* __restrict__ idxI,
                     const float* __restrict__ MEAN, const float* __restrict__ KG,
                     const float* __restrict__ KGT, const float* __restrict__ CGH,
                     float* __restrict__ JNT) {
  int b = blockIdx.x, side = blockIdx.y, p = blockIdx.z;
  int zz = 2 * p + side;
  const int* revs = side ? iRevs : uRevs;
  const float* emb = side ? iEmb : uEmb;
  int idx = side ? idxI[p * 128 + b] : idxU[p * 128 + b];
  const float* Kmat = (side ? KGT : KG) + (size_t)p * 90000;
  __shared__ int toks[60];
  __shared__ float ms[300];
  __shared__ float g_s[300];
  __shared__ float score[60];
  __shared__ float probs[64];
  int t = threadIdx.x;
  if (t < 60) toks[t] = revs[(b * 30 + idx) * 60 + t];
  const float* mrow = MEAN + ((size_t)zz * 128 + b) * 300;
  for (int d = t; d < 300; d += 256) ms[d] = mrow[d];
  __syncthreads();
  for (int k = t; k < 300; k += 256) {
    const float* kr = Kmat + (size_t)k * 300;
    float acc = 0.f;
    for (int e = 0; e < 300; e += 4) {
      float4 kv = *(const float4*)&kr[e];
      acc = fmaf(kv.x, ms[e], acc);
      acc = fmaf(kv.y, ms[e + 1], acc);
      acc = fmaf(kv.z, ms[e + 2], acc);
      acc = fmaf(kv.w, ms[e + 3], acc);
    }
    g_s[k] = acc + CGH[(size_t)zz * 300 + k];
  }
  __syncthreads();
  int w = t >> 6, j = t & 63;
  for (int i = 0; i < 15; ++i) {
    int l = w * 15 + i;
    const float* er = emb + (size_t)toks[l] * 300;
    float partial = 0.f;
#pragma unroll
    for (int c = 0; c < 5; ++c) {
      int k = j + c * 64;
      if (k < 300) partial = fmaf(er[k], g_s[k], partial);
    }
#pragma unroll
    for (int m = 32; m >= 1; m >>= 1) partial += __shfl_xor(partial, m);
    if (j == 0) score[l] = partial;
  }
  __syncthreads();
  if (w == 0) {
    float s = (j < 60) ? score[j] : -3.4e38f;
    float m = s;
#pragma unroll
    for (int mm = 32; mm >= 1; mm >>= 1) m = fmaxf(m, __shfl_xor(m, mm));
    float e = (j < 60) ? expf(s - m) : 0.f;
    float sum = e;
#pragma unroll
    for (int mm = 32; mm >= 1; mm >>= 1) sum += __shfl_xor(sum, mm);
    if (j < 60) probs[j] = e / sum;
  }
  __syncthreads();
  float* outp = JNT + (size_t)b * 1800 + side * 900 + p * 300;
  for (int d = t; d < 300; d += 256) {
    float acc = 0.f;
    for (int l0 = 0; l0 < 60; l0 += 6) {
      float e0 = emb[(size_t)toks[l0 + 0] * 300 + d];
      float e1 = emb[(size_t)toks[l0 + 1] * 300 + d];
      float e2 = emb[(size_t)toks[l0 + 2] * 300 + d];
      float e3 = emb[(size_t)toks[l0 + 3] * 300 + d];
      float e4 = emb[(size_t)toks[l0 + 4] * 300 + d];
      float e5 = emb[(size_t)toks[l0 + 5] * 300 + d];
      acc = fmaf(probs[l0 + 0], e0, acc);
      acc = fmaf(probs[l0 + 1], e1, acc);
      acc = fmaf(probs[l0 + 2], e2, acc);
      acc = fmaf(probs[l0 + 3], e3, acc);
      acc = fmaf(probs[l0 + 4], e4, acc);
      acc = fmaf(probs[l0 + 5], e5, acc);
    }
    outp[d] = acc;
  }
}

// L6: factorization machine.
__global__ __launch_bounds__(64)
void fm_kernel(const float* __restrict__ JNT, const float* __restrict__ w0,
               const float* __restrict__ fw, const float* __restrict__ fv,
               float* __restrict__ out) {
  int b = blockIdx.x, lane = threadIdx.x;
  const float* x = JNT + (size_t)b * 1800;
  float lin = 0.f;
  float t1[10], t2[10];
#pragma unroll
  for (int k = 0; k < 10; ++k) { t1[k] = 0.f; t2[k] = 0.f; }
  for (int j = lane; j < 1800; j += 64) {
    float xv = x[j];
    lin = fmaf(fw[j], xv, lin);
    float xx = xv * xv;
#pragma unroll
    for (int k = 0; k < 10; ++k) {
      float v = fv[j * 10 + k];
      t1[k] = fmaf(xv, v, t1[k]);
      t2[k] = fmaf(xx, v * v, t2[k]);
    }
  }
#pragma unroll
  for (int m = 32; m >= 1; m >>= 1) {
    lin += __shfl_xor(lin, m);
#pragma unroll
    for (int k = 0; k < 10; ++k) {
      t1[k] += __shfl_xor(t1[k], m);
      t2[k] += __shfl_xor(t2[k], m);
    }
  }
  if (lane == 0) {
    float inter = 0.f;
#pragma unroll
    for (int k = 0; k < 10; ++k) inter += t1[k] * t1[k] - t2[k];
    out[b] = w0[0] + lin + 0.5f * inter;
  }
}

extern "C" void kernel_launch(void* const* d_in, const int* in_sizes, int n_in,
                              void* d_out, int out_size, void* d_ws, size_t ws_size,
                              hipStream_t stream) {
  (void)in_sizes; (void)n_in; (void)out_size;
  const int*   uRevs = (const int*)d_in[0];
  const int*   iRevs = (const int*)d_in[1];
  const float* uEmb  = (const float*)d_in[2];
  const float* iEmb  = (const float*)d_in[3];
  const float* g1w   = (const float*)d_in[4];
  const float* g1b   = (const float*)d_in[5];
  const float* g2w   = (const float*)d_in[6];
  const float* g2b   = (const float*)d_in[7];
  const float* Mr    = (const float*)d_in[8];
  const float* Wur   = (const float*)d_in[9];
  const float* bur   = (const float*)d_in[10];
  const float* Wir   = (const float*)d_in[11];
  const float* bir   = (const float*)d_in[12];
  const float* Mw    = (const float*)d_in[13];
  const float* Wuw   = (const float*)d_in[14];
  const float* buw   = (const float*)d_in[15];
  const float* Wiw   = (const float*)d_in[16];
  const float* biw   = (const float*)d_in[17];
  const float* fmw0  = (const float*)d_in[18];
  const float* fmw   = (const float*)d_in[19];
  const float* fmv   = (const float*)d_in[20];
  float* out = (float*)d_out;

  float* ws = (float*)d_ws;
  const size_t NEED_BYTES = (size_t)10300500 * 4;
  if (ws_size < NEED_BYTES) return;

  float* S     = ws + 0;
  float* TPall = ws + 0;
  float* REV   = ws + 3456000;
  float* MEAN  = ws + 3456000;
  float* JNT   = ws + 3916800;
  int*   idxU  = (int*)(ws + 4147200);
  int*   idxI  = idxU + 384;
  float* IPall = ws + 5760000;
  float* A1    = ws + 9216000;
  float* Wp    = ws + 9486000;
  float* KG    = ws + 9756000;
  float* KGT   = ws + 10026000;
  float* Bp    = ws + 10296000;
  float* CGH   = ws + 10296900;
  float* T1S   = ws + 10298700;
  float* T2S   = ws + 10299600;

  // L1: gather-sum
  gather_kernel<<<dim3(1920), dim3(320), 0, stream>>>(
      uRevs, iRevs, uEmb, iEmb, S);

  // L2: review gate + Wp + A1 + stage-A bias pieces
  gate_kernel<<<dim3(774), dim3(256), 0, stream>>>(
      S, g1w, g1b, g2w, g2b, REV,
      Wur, Mr, Mw, Wiw, bur, buw, biw, Wp, A1, T1S, T2S, Bp);

  // L3: TP/IP GEMMs + KG (+KGT) + stage-B bias (CGH)
  {
    Ptr6 P;
    for (int z = 0; z < 3; ++z) {
      P.X[z] = REV;
      P.W[z] = Wp + (size_t)z * 90000;
      P.Bb[z] = Bp + z * 300;
      P.Y[z] = TPall + (size_t)z * 1152000;
      P.X[z + 3] = REV + (size_t)3840 * 300;
      P.W[z + 3] = Wir + (size_t)z * 90000;
      P.Bb[z + 3] = bir + z * 300;
      P.Y[z + 3] = IPall + (size_t)z * 1152000;
    }
    rev128_kernel<<<dim3(987), dim3(256), 0, stream>>>(
        P, Wuw, Wiw, A1, KG, KGT, T1S, T2S, CGH);
  }

  // L4: gumbel-argmax + fused MEAN
  {
    GKeys K;
    for (int p = 0; p < 3; ++p) {
      tf2x32(0u, 42u, 0u, (uint32_t)(2 * p),     &K.v[p * 4],     &K.v[p * 4 + 1]);
      tf2x32(0u, 42u, 0u, (uint32_t)(2 * p + 1), &K.v[p * 4 + 2], &K.v[p * 4 + 3]);
    }
    argmax_mean_kernel<<<dim3(128, 3), dim3(256), 0, stream>>>(
        TPall, IPall, uRevs, iRevs, uEmb, iEmb, idxU, idxI, MEAN, K);
  }

  // L5: word-level reps (gv matvec fused in)
  word_rep_kernel<<<dim3(128, 2, 3), dim3(256), 0, stream>>>(
      uRevs, iRevs, uEmb, iEmb, idxU, idxI, MEAN, KG, KGT, CGH, JNT);

  // L6: factorization machine
  fm_kernel<<<dim3(128), dim3(64), 0, stream>>>(JNT, fmw0, fmw, fmv, out);
}

// Round 15
// 330.612 us; speedup vs baseline: 1.2184x; 1.0006x over previous
//
#include <hip/hip_runtime.h>
#include <stdint.h>
#include <math.h>

// ---------------------------------------------------------------------------
// MPCN (B=128, R=30, L=60, D=300, V=50000, P=3), f32 end-to-end.
// Round 15: exact revert to round 13 (330.8 µs, passing). Round 14's
// bilinear factorization flipped a gumbel selection (absmax 1.2e-4) —
// score-perturbing algebra is off the table; this is the stable optimum.
// ---------------------------------------------------------------------------

__host__ __device__ static inline void tf2x32(uint32_t k0, uint32_t k1,
                                              uint32_t x0, uint32_t x1,
                                              uint32_t* o0, uint32_t* o1) {
  uint32_t ks[3] = {k0, k1, k0 ^ k1 ^ 0x1BD11BDAu};
  x0 += ks[0]; x1 += ks[1];
  const int rotA[4] = {13, 15, 26, 6};
  const int rotB[4] = {17, 29, 16, 24};
#pragma unroll
  for (int i = 0; i < 5; ++i) {
    const int* rot = ((i & 1) == 0) ? rotA : rotB;
#pragma unroll
    for (int j = 0; j < 4; ++j) {
      x0 += x1;
      x1 = (x1 << rot[j]) | (x1 >> (32 - rot[j]));
      x1 ^= x0;
    }
    x0 += ks[(i + 1) % 3];
    x1 += ks[(i + 2) % 3] + (uint32_t)(i + 1);
  }
  *o0 = x0; *o1 = x1;
}

struct GKeys { uint32_t v[12]; };
struct Ptr6 {
  const float* X[6];
  const float* W[6];
  const float* Bb[6];
  float*       Y[6];
};

__device__ static inline float jax_gumbel32(uint32_t k0, uint32_t k1, uint32_t idx) {
  uint32_t o0, o1;
  tf2x32(k0, k1, 0u, idx, &o0, &o1);
  uint32_t bits = o0 ^ o1;
  float f = __uint_as_float((bits >> 9) | 0x3f800000u) - 1.0f;
  float u = (f > 0.0f) ? f : 1.17549435e-38f;
  return -logf(-logf(u));
}

#define MODE_NN 0
#define MODE_NT 1
#define MODE_TN 2

// 64x64 f32 GEMM tile, K=N=300, ld=300, caller-provided LDS arena
// (needs 2*20*68 = 2720 floats). Optional transposed second output Yt.
template <int MODE, bool BIAS>
__device__ __forceinline__ void gemm_tile(float* __restrict__ sm,
                                          const float* __restrict__ X,
                                          const float* __restrict__ W,
                                          const float* __restrict__ bias,
                                          float* __restrict__ Y,
                                          float* __restrict__ Yt,
                                          int M, int bm, int n0, int t) {
  float (*Xs)[68] = (float(*)[68])sm;
  float (*Ws_)[68] = (float(*)[68])(sm + 20 * 68);
  const bool act = t < 256;
  int tm4 = ((t >> 4) & 15) * 4;
  int tn4 = (t & 15) * 4;
  float acc[4][4] = {{0.f}};
  int xm = t >> 2;
  int xk = (t & 3) * 5;
  for (int k0 = 0; k0 < 300; k0 += 20) {
    if (act) {
      if (MODE == MODE_TN) {
#pragma unroll
        for (int i = 0; i < 5; ++i) {
          int flat = t + i * 256;
          int kk = flat >> 6, nn = flat & 63;
          int r = bm + nn;
          Xs[kk][nn] = (r < 300) ? X[(size_t)(k0 + kk) * 300 + r] : 0.f;
        }
      } else {
        int rr = bm + xm; if (rr >= M) rr = M - 1;
        const float* xp = X + (size_t)rr * 300 + k0 + xk;
#pragma unroll
        for (int j = 0; j < 5; ++j) Xs[xk + j][xm] = xp[j];
      }
      if (MODE == MODE_NT) {
        int d = n0 + xm;
        bool ok = d < 300;
        const float* wp = W + (size_t)d * 300 + k0 + xk;
#pragma unroll
        for (int j = 0; j < 5; ++j) Ws_[xk + j][xm] = ok ? wp[j] : 0.f;
      } else {
#pragma unroll
        for (int i = 0; i < 5; ++i) {
          int flat = t + i * 256;
          int kk = flat >> 6, nn = flat & 63;
          int col = n0 + nn;
          Ws_[kk][nn] = (col < 300) ? W[(size_t)(k0 + kk) * 300 + col] : 0.f;
        }
      }
    }
    __syncthreads();
    if (act) {
#pragma unroll
      for (int kk = 0; kk < 20; ++kk) {
        const float4 a = *(const float4*)&Xs[kk][tm4];
        const float4 w = *(const float4*)&Ws_[kk][tn4];
        float av[4] = {a.x, a.y, a.z, a.w};
        float wv[4] = {w.x, w.y, w.z, w.w};
#pragma unroll
        for (int i = 0; i < 4; ++i)
#pragma unroll
          for (int j = 0; j < 4; ++j)
            acc[i][j] = fmaf(av[i], wv[j], acc[i][j]);
      }
    }
    __syncthreads();
  }
  if (!act) return;
  float bv[4] = {0.f, 0.f, 0.f, 0.f};
  if (BIAS) {
#pragma unroll
    for (int j = 0; j < 4; ++j) {
      int col = n0 + tn4 + j;
      if (col < 300) bv[j] = bias[col];
    }
  }
#pragma unroll
  for (int i = 0; i < 4; ++i) {
    int row = bm + tm4 + i;
    if (row < M) {
      float* yp = Y + (size_t)row * 300 + n0 + tn4;
#pragma unroll
      for (int j = 0; j < 4; ++j) {
        int col = n0 + tn4 + j;
        if (col < 300) yp[j] = acc[i][j] + bv[j];
      }
    }
  }
  if (Yt) {
#pragma unroll
    for (int i = 0; i < 4; ++i) {
      int row = bm + tm4 + i;
      if (row < 300) {
#pragma unroll
        for (int j = 0; j < 4; ++j) {
          int col = n0 + tn4 + j;
          if (col < 300) Yt[(size_t)col * 300 + row] = acc[i][j];
        }
      }
    }
  }
}

// L1: gather-sum, minimal-resource, 15-deep ILP (ascending-l adds).
__global__ __launch_bounds__(320)
void gather_kernel(const int* __restrict__ uRevs, const int* __restrict__ iRevs,
                   const float* __restrict__ uEmb, const float* __restrict__ iEmb,
                   float* __restrict__ S) {
  int bid = blockIdx.x;   // 0..1919
  int t = threadIdx.x;
  __shared__ int toks[4][60];
  if (t < 240) {
    int rr = t / 60, l = t - rr * 60;
    int grow = bid * 4 + rr;
    int side = grow / 3840;
    int row = grow - side * 3840;
    const int* revs = side ? iRevs : uRevs;
    toks[rr][l] = revs[row * 60 + l];
  }
  __syncthreads();
  if (t < 300) {
    int sub = t / 75;
    int q4 = (t - sub * 75) * 4;
    int grow = bid * 4 + sub;
    int side = grow / 3840;
    const float* emb = side ? iEmb : uEmb;
    const int* tk = toks[sub];
    float ax = 0.f, ay = 0.f, az = 0.f, aw = 0.f;
#pragma unroll
    for (int l0 = 0; l0 < 60; l0 += 15) {
      float4 v[15];
#pragma unroll
      for (int qq = 0; qq < 15; ++qq)
        v[qq] = *(const float4*)&emb[(size_t)tk[l0 + qq] * 300 + q4];
#pragma unroll
      for (int qq = 0; qq < 15; ++qq) {
        ax += v[qq].x; ay += v[qq].y; az += v[qq].z; aw += v[qq].w;
      }
    }
    float4 r = {ax, ay, az, aw};
    *(float4*)&S[(size_t)grow * 300 + q4] = r;
  }
}

// L2: review gate (0..599, conflict-free float4 staging) + Wp (600..674) +
// A1 (675..749) + stage-A bias pieces (750..773).
__global__ __launch_bounds__(256)
void gate_kernel(const float* __restrict__ S,
                 const float* __restrict__ g1w, const float* __restrict__ g1b,
                 const float* __restrict__ g2w, const float* __restrict__ g2b,
                 float* __restrict__ REV,
                 const float* __restrict__ Wur, const float* __restrict__ Mr,
                 const float* __restrict__ Mw, const float* __restrict__ Wiw,
                 const float* __restrict__ bur, const float* __restrict__ buw,
                 const float* __restrict__ biw,
                 float* __restrict__ Wp, float* __restrict__ A1,
                 float* __restrict__ T1S, float* __restrict__ T2S,
                 float* __restrict__ Bp) {
  __shared__ __align__(16) float arena[4080];  // 16320 B
  int bid = blockIdx.x, t = threadIdx.x;
  if (bid < 600) {
    float (*Xs)[68] = (float(*)[68])arena;
    float (*Ws1)[68] = (float(*)[68])(arena + 1360);
    float (*Ws2)[68] = (float(*)[68])(arena + 2720);
    int bm = (bid / 5) * 64;
    int n0 = (bid % 5) * 64;
    int tm4 = (t >> 4) * 4;
    int tn4 = (t & 15) * 4;
    float acc1[4][4] = {{0.f}};
    float acc2[4][4] = {{0.f}};
    for (int k0 = 0; k0 < 300; k0 += 20) {
      // X panel: 320 float4 = 64 rows x 5 q; row-minor map (row = fid&63)
      for (int fid = t; fid < 320; fid += 256) {
        int row = fid & 63, q = fid >> 6;
        float4 v = *(const float4*)&S[(size_t)(bm + row) * 300 + k0 + q * 4];
        int kq = q * 4;
        Xs[kq + 0][row] = v.x; Xs[kq + 1][row] = v.y;
        Xs[kq + 2][row] = v.z; Xs[kq + 3][row] = v.w;
      }
      // W1 panel (NT, zero-fill d>=300)
      for (int fid = t; fid < 320; fid += 256) {
        int dl = fid & 63, q = fid >> 6;
        int d = n0 + dl;
        float4 v = {0.f, 0.f, 0.f, 0.f};
        if (d < 300) v = *(const float4*)&g1w[(size_t)d * 300 + k0 + q * 4];
        int kq = q * 4;
        Ws1[kq + 0][dl] = v.x; Ws1[kq + 1][dl] = v.y;
        Ws1[kq + 2][dl] = v.z; Ws1[kq + 3][dl] = v.w;
      }
      // W2 panel
      for (int fid = t; fid < 320; fid += 256) {
        int dl = fid & 63, q = fid >> 6;
        int d = n0 + dl;
        float4 v = {0.f, 0.f, 0.f, 0.f};
        if (d < 300) v = *(const float4*)&g2w[(size_t)d * 300 + k0 + q * 4];
        int kq = q * 4;
        Ws2[kq + 0][dl] = v.x; Ws2[kq + 1][dl] = v.y;
        Ws2[kq + 2][dl] = v.z; Ws2[kq + 3][dl] = v.w;
      }
      __syncthreads();
#pragma unroll
      for (int kk = 0; kk < 20; ++kk) {
        const float4 a = *(const float4*)&Xs[kk][tm4];
        const float4 w1 = *(const float4*)&Ws1[kk][tn4];
        const float4 w2 = *(const float4*)&Ws2[kk][tn4];
        float av[4] = {a.x, a.y, a.z, a.w};
        float w1v[4] = {w1.x, w1.y, w1.z, w1.w};
        float w2v[4] = {w2.x, w2.y, w2.z, w2.w};
#pragma unroll
        for (int i = 0; i < 4; ++i)
#pragma unroll
          for (int j = 0; j < 4; ++j) {
            acc1[i][j] = fmaf(av[i], w1v[j], acc1[i][j]);
            acc2[i][j] = fmaf(av[i], w2v[j], acc2[i][j]);
          }
      }
      __syncthreads();
    }
#pragma unroll
    for (int i = 0; i < 4; ++i) {
      int row = bm + tm4 + i;
      float* yp = REV + (size_t)row * 300 + n0 + tn4;
#pragma unroll
      for (int j = 0; j < 4; ++j) {
        int col = n0 + tn4 + j;
        if (col < 300) {
          float a = acc1[i][j] + g1b[col];
          float b = acc2[i][j] + g2b[col];
          yp[j] = (1.f / (1.f + expf(-a))) * tanhf(b);
        }
      }
    }
  } else if (bid < 675) {
    int zi = bid - 600, z = zi / 25, r = zi % 25;
    gemm_tile<MODE_TN, false>(arena, Wur + (size_t)z * 90000, Mr + (size_t)z * 90000,
                              nullptr, Wp + (size_t)z * 90000, nullptr,
                              300, (r / 5) * 64, (r % 5) * 64, t);
  } else if (bid < 750) {
    int zi = bid - 675, z = zi / 25, r = zi % 25;
    gemm_tile<MODE_NN, false>(arena, Mw + (size_t)z * 90000, Wiw + (size_t)z * 90000,
                              nullptr, A1 + (size_t)z * 90000, nullptr,
                              300, (r / 5) * 64, (r % 5) * 64, t);
  } else if (bid < 762) {
    // t1s[z][e] = sum_k Mw[z][e,k] * biw[z][k]  (row-form, wave-shfl dots)
    int idx = bid - 750, z = idx >> 2, qb = idx & 3;
    const float* Mwz = Mw + (size_t)z * 90000;
    const float* bw = biw + z * 300;
    int w = t >> 6, j = t & 63;
    int e0 = qb * 75;
    for (int i = 0; i < 19; ++i) {
      int el = w + 4 * i;
      if (el < 75) {
        int e = e0 + el;
        float partial = 0.f;
#pragma unroll
        for (int c = 0; c < 5; ++c) {
          int k = j + c * 64;
          if (k < 300) partial = fmaf(Mwz[(size_t)e * 300 + k], bw[k], partial);
        }
#pragma unroll
        for (int m = 32; m >= 1; m >>= 1) partial += __shfl_xor(partial, m);
        if (j == 0) T1S[z * 300 + e] = partial;
      }
    }
  } else if (bid < 768) {
    // t2s[z][e] = sum_d Mw[z][d,e] * buw[z][d]  (column-form, ILP-15)
    int idx = bid - 762, z = idx >> 1, half = idx & 1;
    const float* Mwz = Mw + (size_t)z * 90000;
    float* vb = arena;
    for (int d = t; d < 300; d += 256) vb[d] = buw[z * 300 + d];
    __syncthreads();
    if (t < 150) {
      int e = half * 150 + t;
      float a = 0.f;
      for (int d0 = 0; d0 < 300; d0 += 15) {
        float mv[15];
#pragma unroll
        for (int q = 0; q < 15; ++q) mv[q] = Mwz[(size_t)(d0 + q) * 300 + e];
#pragma unroll
        for (int q = 0; q < 15; ++q) a = fmaf(mv[q], vb[d0 + q], a);
      }
      T2S[z * 300 + e] = a;
    }
  } else {
    // Bp[z][e] = sum_d Mr[z][d,e] * bur[z][d]  (ascending-d, bitwise kept)
    int idx = bid - 768, z = idx >> 1, half = idx & 1;
    const float* Mrz = Mr + (size_t)z * 90000;
    float* vb = arena;
    for (int d = t; d < 300; d += 256) vb[d] = bur[z * 300 + d];
    __syncthreads();
    if (t < 150) {
      int e = half * 150 + t;
      float a = 0.f;
      for (int d0 = 0; d0 < 300; d0 += 15) {
        float mv[15];
#pragma unroll
        for (int q = 0; q < 15; ++q) mv[q] = Mrz[(size_t)(d0 + q) * 300 + e];
#pragma unroll
        for (int q = 0; q < 15; ++q) a = fmaf(mv[q], vb[d0 + q], a);
      }
      Bp[z * 300 + e] = a;
    }
  }
}

// L3: TP/IP GEMMs (0..899, conflict-free float4 staging) + KG (900..974) +
// stage-B (975..986).
__global__ __launch_bounds__(256)
void rev128_kernel(Ptr6 P, const float* __restrict__ Wuw,
                   const float* __restrict__ Wiw,
                   const float* __restrict__ A1,
                   float* __restrict__ KG, float* __restrict__ KGT,
                   const float* __restrict__ T1S, const float* __restrict__ T2S,
                   float* __restrict__ CGH) {
  __shared__ __align__(16) float arena[4080];  // 16320 B
  int bid = blockIdx.x, t = threadIdx.x;
  if (bid >= 975) {
    int idx = bid - 975;
    int z = idx >> 2;
    int r2 = idx & 3;
    int which = r2 >> 1, half = r2 & 1;
    const float* W = (which ? Wiw : Wuw) + (size_t)z * 90000;
    const float* tv = (which ? T2S : T1S) + z * 300;
    float* vb = arena;
    for (int d = t; d < 300; d += 256) vb[d] = tv[d];
    __syncthreads();
    if (t < 150) {
      int k = half * 150 + t;
      float a = 0.f;
      for (int d0 = 0; d0 < 300; d0 += 15) {
        float mv[15];
#pragma unroll
        for (int q = 0; q < 15; ++q) mv[q] = W[(size_t)(d0 + q) * 300 + k];
#pragma unroll
        for (int q = 0; q < 15; ++q) a = fmaf(mv[q], vb[d0 + q], a);
      }
      CGH[(size_t)(2 * z + which) * 300 + k] = a;
    }
    return;
  }
  if (bid >= 900) {
    int zi = bid - 900, z = zi / 25, r = zi % 25;
    gemm_tile<MODE_TN, false>(arena, Wuw + (size_t)z * 90000, A1 + (size_t)z * 90000,
                              nullptr, KG + (size_t)z * 90000,
                              KGT + (size_t)z * 90000,
                              300, (r / 5) * 64, (r % 5) * 64, t);
    return;
  }
  int z = bid / 150;
  int rem = bid - z * 150;
  int bm = (rem % 30) * 128;
  int n0 = (rem / 30) * 64;
  const bool nt = z >= 3;
  const float* __restrict__ X = P.X[z];
  const float* __restrict__ W = P.W[z];
  const float* __restrict__ bias = P.Bb[z];
  float* __restrict__ Y = P.Y[z];
  float (*Xs)[136] = (float(*)[136])arena;            // 20*136 = 2720
  float (*Ws_)[68] = (float(*)[68])(arena + 2720);    // 20*68  = 1360
  int tm8 = (t >> 4) * 8, tn4 = (t & 15) * 4;
  float acc[8][4] = {{0.f}};
  for (int k0 = 0; k0 < 300; k0 += 20) {
    // X panel: 640 float4 = 128 rows x 5 q; row-minor map (row = fid&127)
    for (int fid = t; fid < 640; fid += 256) {
      int row = fid & 127, q = fid >> 7;
      float4 v = *(const float4*)&X[(size_t)(bm + row) * 300 + k0 + q * 4];
      int kq = q * 4;
      Xs[kq + 0][row] = v.x; Xs[kq + 1][row] = v.y;
      Xs[kq + 2][row] = v.z; Xs[kq + 3][row] = v.w;
    }
    // W panel: 320 float4
    if (nt) {
      for (int fid = t; fid < 320; fid += 256) {
        int dl = fid & 63, q = fid >> 6;
        int d = n0 + dl;
        float4 v = {0.f, 0.f, 0.f, 0.f};
        if (d < 300) v = *(const float4*)&W[(size_t)d * 300 + k0 + q * 4];
        int kq = q * 4;
        Ws_[kq + 0][dl] = v.x; Ws_[kq + 1][dl] = v.y;
        Ws_[kq + 2][dl] = v.z; Ws_[kq + 3][dl] = v.w;
      }
    } else {
      for (int fid = t; fid < 320; fid += 256) {
        int kk = fid >> 4, ng = fid & 15;
        int col = n0 + ng * 4;
        float4 v = {0.f, 0.f, 0.f, 0.f};
        if (col + 3 < 300) v = *(const float4*)&W[(size_t)(k0 + kk) * 300 + col];
        *(float4*)&Ws_[kk][ng * 4] = v;
      }
    }
    __syncthreads();
#pragma unroll
    for (int kk = 0; kk < 20; ++kk) {
      const float4 a0 = *(const float4*)&Xs[kk][tm8];
      const float4 a1 = *(const float4*)&Xs[kk][tm8 + 4];
      const float4 w = *(const float4*)&Ws_[kk][tn4];
      float av[8] = {a0.x, a0.y, a0.z, a0.w, a1.x, a1.y, a1.z, a1.w};
      float wv[4] = {w.x, w.y, w.z, w.w};
#pragma unroll
      for (int i = 0; i < 8; ++i)
#pragma unroll
        for (int j = 0; j < 4; ++j)
          acc[i][j] = fmaf(av[i], wv[j], acc[i][j]);
    }
    __syncthreads();
  }
  float bv[4];
#pragma unroll
  for (int j = 0; j < 4; ++j) {
    int col = n0 + tn4 + j;
    bv[j] = (col < 300) ? bias[col] : 0.f;
  }
#pragma unroll
  for (int i = 0; i < 8; ++i) {
    float* yp = Y + (size_t)(bm + tm8 + i) * 300 + n0 + tn4;
#pragma unroll
    for (int j = 0; j < 4; ++j) {
      int col = n0 + tn4 + j;
      if (col < 300) yp[j] = acc[i][j] + bv[j];
    }
  }
}

// L4: review scores (float4 dot) + gumbel-argmax + fused MEAN.
__global__ __launch_bounds__(256)
void argmax_mean_kernel(const float* __restrict__ Tall, const float* __restrict__ Iall,
                        const int* __restrict__ uRevs, const int* __restrict__ iRevs,
                        const float* __restrict__ uEmb, const float* __restrict__ iEmb,
                        int* __restrict__ idxU, int* __restrict__ idxI,
                        float* __restrict__ MEAN, GKeys K) {
  int b = blockIdx.x, z = blockIdx.y, t = threadIdx.x;
  uint32_t ku0 = K.v[z * 4], ku1 = K.v[z * 4 + 1];
  uint32_t ki0 = K.v[z * 4 + 2], ki1 = K.v[z * 4 + 3];
  __shared__ __align__(16) float Is[30 * 304];
  __shared__ float Sc[900];
  __shared__ float us[30], vs[30];
  __shared__ int selU, selI;
  __shared__ int toksI_s[60], toksU_s[60];
  const float* Tb = Tall + (size_t)z * 1152000 + (size_t)b * 9000;
  const float* Ib = Iall + (size_t)z * 1152000 + (size_t)b * 9000;
  for (int fc = t; fc < 2250; fc += 256) {
    int r = fc / 75, q = fc - r * 75;
    *(float4*)&Is[r * 304 + q * 4] = *(const float4*)&Ib[r * 300 + q * 4];
  }
  __syncthreads();
  for (int id = t; id < 900; id += 256) {
    int r = id / 30, c = id - r * 30;
    const float* tr = Tb + r * 300;
    const float* ic = Is + c * 304;
    float acc = 0.f;
    for (int k = 0; k < 300; k += 4) {
      float4 a = *(const float4*)&tr[k];
      float4 w = *(const float4*)&ic[k];
      acc = fmaf(a.x, w.x, acc);
      acc = fmaf(a.y, w.y, acc);
      acc = fmaf(a.z, w.z, acc);
      acc = fmaf(a.w, w.w, acc);
    }
    Sc[id] = acc;
  }
  __syncthreads();
  if (t < 30) {
    float m = -3.4e38f;
    for (int c = 0; c < 30; ++c) m = fmaxf(m, Sc[t * 30 + c]);
    us[t] = m + jax_gumbel32(ku0, ku1, (uint32_t)(b * 30 + t));
  } else if (t >= 64 && t < 94) {
    int s = t - 64;
    float m = -3.4e38f;
    for (int r = 0; r < 30; ++r) m = fmaxf(m, Sc[r * 30 + s]);
    vs[s] = m + jax_gumbel32(ki0, ki1, (uint32_t)(b * 30 + s));
  }
  __syncthreads();
  if (t == 0) {
    int best = 0; float bvv = us[0];
    for (int r = 1; r < 30; ++r) { if (us[r] > bvv) { bvv = us[r]; best = r; } }
    idxU[z * 128 + b] = best; selU = best;
  } else if (t == 1) {
    int best = 0; float bvv = vs[0];
    for (int s = 1; s < 30; ++s) { if (vs[s] > bvv) { bvv = vs[s]; best = s; } }
    idxI[z * 128 + b] = best; selI = best;
  }
  __syncthreads();
  if (t < 60) toksI_s[t] = iRevs[(b * 30 + selI) * 60 + t];
  else if (t >= 64 && t < 124) toksU_s[t - 64] = uRevs[(b * 30 + selU) * 60 + (t - 64)];
  __syncthreads();
  for (int dd = t; dd < 600; dd += 256) {
    int side = dd / 300;
    int d = dd - side * 300;
    const int* tk = side ? toksU_s : toksI_s;
    const float* em = side ? uEmb : iEmb;
    float acc = 0.f;
#pragma unroll
    for (int l0 = 0; l0 < 60; l0 += 10) {
      float v[10];
#pragma unroll
      for (int q = 0; q < 10; ++q)
        v[q] = em[(size_t)tk[l0 + q] * 300 + d];
#pragma unroll
      for (int q = 0; q < 10; ++q) acc += v[q];
    }
    MEAN[((size_t)(2 * z + side) * 128 + b) * 300 + d] = acc * (1.f / 60.f);
  }
}

// L5: per (b, side, p): gv = MEAN@K + c (fused); scores; softmax; weighted sum.
__global__ __launch_bounds__(256)
void word_rep_kernel(const int* __restrict__ uRevs, const int* __restrict__ iRevs,
                     const float* __restrict__ uEmb, const float* __restrict__ iEmb,
                     const int* __restrict__ idxU, const int* __restrict__ idxI,
                     const float* __restrict__ MEAN, const float* __restrict__ KG,
                     const float* __restrict__ KGT, const float* __restrict__ CGH,
                     float* __restrict__ JNT) {
  int b = blockIdx.x, side = blockIdx.y, p = blockIdx.z;
  int zz = 2 * p + side;
  const int* revs = side ? iRevs : uRevs;
  const float* emb = side ? iEmb : uEmb;
  int idx = side ? idxI[p * 128 + b] : idxU[p * 128 + b];
  const float* Kmat = (side ? KGT : KG) + (size_t)p * 90000;
  __shared__ int toks[60];
  __shared__ float ms[300];
  __shared__ float g_s[300];
  __shared__ float score[60];
  __shared__ float probs[64];
  int t = threadIdx.x;
  if (t < 60) toks[t] = revs[(b * 30 + idx) * 60 + t];
  const float* mrow = MEAN + ((size_t)zz * 128 + b) * 300;
  for (int d = t; d < 300; d += 256) ms[d] = mrow[d];
  __syncthreads();
  for (int k = t; k < 300; k += 256) {
    const float* kr = Kmat + (size_t)k * 300;
    float acc = 0.f;
    for (int e = 0; e < 300; e += 4) {
      float4 kv = *(const float4*)&kr[e];
      acc = fmaf(kv.x, ms[e], acc);
      acc = fmaf(kv.y, ms[e + 1], acc);
      acc = fmaf(kv.z, ms[e + 2], acc);
      acc = fmaf(kv.w, ms[e + 3], acc);
    }
    g_s[k] = acc + CGH[(size_t)zz * 300 + k];
  }
  __syncthreads();
  int w = t >> 6, j = t & 63;
  for (int i = 0; i < 15; ++i) {
    int l = w * 15 + i;
    const float* er = emb + (size_t)toks[l] * 300;
    float partial = 0.f;
#pragma unroll
    for (int c = 0; c < 5; ++c) {
      int k = j + c * 64;
      if (k < 300) partial = fmaf(er[k], g_s[k], partial);
    }
#pragma unroll
    for (int m = 32; m >= 1; m >>= 1) partial += __shfl_xor(partial, m);
    if (j == 0) score[l] = partial;
  }
  __syncthreads();
  if (w == 0) {
    float s = (j < 60) ? score[j] : -3.4e38f;
    float m = s;
#pragma unroll
    for (int mm = 32; mm >= 1; mm >>= 1) m = fmaxf(m, __shfl_xor(m, mm));
    float e = (j < 60) ? expf(s - m) : 0.f;
    float sum = e;
#pragma unroll
    for (int mm = 32; mm >= 1; mm >>= 1) sum += __shfl_xor(sum, mm);
    if (j < 60) probs[j] = e / sum;
  }
  __syncthreads();
  float* outp = JNT + (size_t)b * 1800 + side * 900 + p * 300;
  for (int d = t; d < 300; d += 256) {
    float acc = 0.f;
    for (int l0 = 0; l0 < 60; l0 += 6) {
      float e0 = emb[(size_t)toks[l0 + 0] * 300 + d];
      float e1 = emb[(size_t)toks[l0 + 1] * 300 + d];
      float e2 = emb[(size_t)toks[l0 + 2] * 300 + d];
      float e3 = emb[(size_t)toks[l0 + 3] * 300 + d];
      float e4 = emb[(size_t)toks[l0 + 4] * 300 + d];
      float e5 = emb[(size_t)toks[l0 + 5] * 300 + d];
      acc = fmaf(probs[l0 + 0], e0, acc);
      acc = fmaf(probs[l0 + 1], e1, acc);
      acc = fmaf(probs[l0 + 2], e2, acc);
      acc = fmaf(probs[l0 + 3], e3, acc);
      acc = fmaf(probs[l0 + 4], e4, acc);
      acc = fmaf(probs[l0 + 5], e5, acc);
    }
    outp[d] = acc;
  }
}

// L6: factorization machine.
__global__ __launch_bounds__(64)
void fm_kernel(const float* __restrict__ JNT, const float* __restrict__ w0,
               const float* __restrict__ fw, const float* __restrict__ fv,
               float* __restrict__ out) {
  int b = blockIdx.x, lane = threadIdx.x;
  const float* x = JNT + (size_t)b * 1800;
  float lin = 0.f;
  float t1[10], t2[10];
#pragma unroll
  for (int k = 0; k < 10; ++k) { t1[k] = 0.f; t2[k] = 0.f; }
  for (int j = lane; j < 1800; j += 64) {
    float xv = x[j];
    lin = fmaf(fw[j], xv, lin);
    float xx = xv * xv;
#pragma unroll
    for (int k = 0; k < 10; ++k) {
      float v = fv[j * 10 + k];
      t1[k] = fmaf(xv, v, t1[k]);
      t2[k] = fmaf(xx, v * v, t2[k]);
    }
  }
#pragma unroll
  for (int m = 32; m >= 1; m >>= 1) {
    lin += __shfl_xor(lin, m);
#pragma unroll
    for (int k = 0; k < 10; ++k) {
      t1[k] += __shfl_xor(t1[k], m);
      t2[k] += __shfl_xor(t2[k], m);
    }
  }
  if (lane == 0) {
    float inter = 0.f;
#pragma unroll
    for (int k = 0; k < 10; ++k) inter += t1[k] * t1[k] - t2[k];
    out[b] = w0[0] + lin + 0.5f * inter;
  }
}

extern "C" void kernel_launch(void* const* d_in, const int* in_sizes, int n_in,
                              void* d_out, int out_size, void* d_ws, size_t ws_size,
                              hipStream_t stream) {
  (void)in_sizes; (void)n_in; (void)out_size;
  const int*   uRevs = (const int*)d_in[0];
  const int*   iRevs = (const int*)d_in[1];
  const float* uEmb  = (const float*)d_in[2];
  const float* iEmb  = (const float*)d_in[3];
  const float* g1w   = (const float*)d_in[4];
  const float* g1b   = (const float*)d_in[5];
  const float* g2w   = (const float*)d_in[6];
  const float* g2b   = (const float*)d_in[7];
  const float* Mr    = (const float*)d_in[8];
  const float* Wur   = (const float*)d_in[9];
  const float* bur   = (const float*)d_in[10];
  const float* Wir   = (const float*)d_in[11];
  const float* bir   = (const float*)d_in[12];
  const float* Mw    = (const float*)d_in[13];
  const float* Wuw   = (const float*)d_in[14];
  const float* buw   = (const float*)d_in[15];
  const float* Wiw   = (const float*)d_in[16];
  const float* biw   = (const float*)d_in[17];
  const float* fmw0  = (const float*)d_in[18];
  const float* fmw   = (const float*)d_in[19];
  const float* fmv   = (const float*)d_in[20];
  float* out = (float*)d_out;

  float* ws = (float*)d_ws;
  const size_t NEED_BYTES = (size_t)10300500 * 4;
  if (ws_size < NEED_BYTES) return;

  float* S     = ws + 0;
  float* TPall = ws + 0;
  float* REV   = ws + 3456000;
  float* MEAN  = ws + 3456000;
  float* JNT   = ws + 3916800;
  int*   idxU  = (int*)(ws + 4147200);
  int*   idxI  = idxU + 384;
  float* IPall = ws + 5760000;
  float* A1    = ws + 9216000;
  float* Wp    = ws + 9486000;
  float* KG    = ws + 9756000;
  float* KGT   = ws + 10026000;
  float* Bp    = ws + 10296000;
  float* CGH   = ws + 10296900;
  float* T1S   = ws + 10298700;
  float* T2S   = ws + 10299600;

  // L1: gather-sum
  gather_kernel<<<dim3(1920), dim3(320), 0, stream>>>(
      uRevs, iRevs, uEmb, iEmb, S);

  // L2: review gate + Wp + A1 + stage-A bias pieces
  gate_kernel<<<dim3(774), dim3(256), 0, stream>>>(
      S, g1w, g1b, g2w, g2b, REV,
      Wur, Mr, Mw, Wiw, bur, buw, biw, Wp, A1, T1S, T2S, Bp);

  // L3: TP/IP GEMMs + KG (+KGT) + stage-B bias (CGH)
  {
    Ptr6 P;
    for (int z = 0; z < 3; ++z) {
      P.X[z] = REV;
      P.W[z] = Wp + (size_t)z * 90000;
      P.Bb[z] = Bp + z * 300;
      P.Y[z] = TPall + (size_t)z * 1152000;
      P.X[z + 3] = REV + (size_t)3840 * 300;
      P.W[z + 3] = Wir + (size_t)z * 90000;
      P.Bb[z + 3] = bir + z * 300;
      P.Y[z + 3] = IPall + (size_t)z * 1152000;
    }
    rev128_kernel<<<dim3(987), dim3(256), 0, stream>>>(
        P, Wuw, Wiw, A1, KG, KGT, T1S, T2S, CGH);
  }

  // L4: gumbel-argmax + fused MEAN
  {
    GKeys K;
    for (int p = 0; p < 3; ++p) {
      tf2x32(0u, 42u, 0u, (uint32_t)(2 * p),     &K.v[p * 4],     &K.v[p * 4 + 1]);
      tf2x32(0u, 42u, 0u, (uint32_t)(2 * p + 1), &K.v[p * 4 + 2], &K.v[p * 4 + 3]);
    }
    argmax_mean_kernel<<<dim3(128, 3), dim3(256), 0, stream>>>(
        TPall, IPall, uRevs, iRevs, uEmb, iEmb, idxU, idxI, MEAN, K);
  }

  // L5: word-level reps (gv matvec fused in)
  word_rep_kernel<<<dim3(128, 2, 3), dim3(256), 0, stream>>>(
      uRevs, iRevs, uEmb, iEmb, idxU, idxI, MEAN, KG, KGT, CGH, JNT);

  // L6: factorization machine
  fm_kernel<<<dim3(128), dim3(64), 0, stream>>>(JNT, fmw0, fmw, fmv, out);
}